// Round 3
// baseline (776.525 us; speedup 1.0000x reference)
//
#include <hip/hip_runtime.h>
#include <hip/hip_bf16.h>

// Problem constants
constexpr int Bc = 2, Nc = 1024, HIDc = 2048, Hc = 32, Dc = 64, HKVc = 8, NCc = 16;

typedef unsigned short bfu;  // raw bf16 bits
typedef __attribute__((ext_vector_type(8))) short frag_ab;  // 8 bf16 (4 VGPRs)
typedef __attribute__((ext_vector_type(4))) float frag_cd;  // 4 fp32 acc

__device__ __forceinline__ bfu f2bf(float f) {
  unsigned int u = __float_as_uint(f);
  unsigned int r = u + 0x7fffu + ((u >> 16) & 1u);  // RNE
  return (bfu)(r >> 16);
}
__device__ __forceinline__ ushort4 pack4(float4 v) {
  ushort4 r; r.x = f2bf(v.x); r.y = f2bf(v.y); r.z = f2bf(v.z); r.w = f2bf(v.w);
  return r;
}

// async global->LDS, 16B per lane (m97 pattern: lane-linear staging layout)
__device__ __forceinline__ void gl16(const bfu* g, bfu* l) {
  __builtin_amdgcn_global_load_lds(
      (const __attribute__((address_space(1))) void*)g,
      (__attribute__((address_space(3))) void*)l, 16, 0, 0);
}

// ---------------------------------------------------------------------------
// Flat cast fp32 -> bf16 (4 elements/thread)
// ---------------------------------------------------------------------------
__global__ __launch_bounds__(256) void cast_bf16_k(
    const float* __restrict__ in, bfu* __restrict__ out)
{
  const size_t i = ((size_t)blockIdx.x * 256 + threadIdx.x) * 4;
  *(ushort4*)(out + i) = pack4(*(const float4*)(in + i));
}

// ---------------------------------------------------------------------------
// Transpose + cast: W fp32 [K][N] -> WT bf16 [N][K].  32x32 tiles, 256 thr.
// ---------------------------------------------------------------------------
__global__ __launch_bounds__(256) void transpose_cast_k(
    const float* __restrict__ W, bfu* __restrict__ WT, int K, int N)
{
  __shared__ float t[32][33];
  const int bn = blockIdx.x * 32, bk = blockIdx.y * 32;
  const int x = threadIdx.x & 31, y = threadIdx.x >> 5;  // 32x8
#pragma unroll
  for (int i = 0; i < 32; i += 8)
    t[y + i][x] = W[(size_t)(bk + y + i) * N + bn + x];
  __syncthreads();
#pragma unroll
  for (int i = 0; i < 32; i += 8)
    WT[(size_t)(bn + y + i) * K + bk + x] = f2bf(t[x][y + i]);
}

// ---------------------------------------------------------------------------
// V transpose + cast: v fp32 [b,n,hk,dv] -> vt bf16 [b,hk,dv,n].  256 blocks.
// ---------------------------------------------------------------------------
__global__ __launch_bounds__(256) void transpose_v_k(
    const float* __restrict__ v, bfu* __restrict__ vt)
{
  __shared__ __align__(16) bfu T[64][72];
  const int blk = blockIdx.x;
  const int nt = blk & 15, bh = blk >> 4;  // n-tile, b*8+hk
  const int hk = bh & 7, b = bh >> 3;
  const int tid = threadIdx.x;
  const int n = tid >> 2, dv0 = (tid & 3) * 16;
  const float* src = v + ((size_t)(b * Nc + nt * 64 + n) * 8 + hk) * 64 + dv0;
#pragma unroll
  for (int e = 0; e < 16; ++e) T[dv0 + e][n] = f2bf(src[e]);
  __syncthreads();
  const int r = tid >> 3, c = (tid & 7) * 8;
#pragma unroll
  for (int hh = 0; hh < 2; ++hh) {
    const int dv = r + hh * 32;
    *(uint4*)(vt + ((size_t)(bh * 64 + dv)) * 1024 + nt * 64 + c) =
        *(const uint4*)&T[dv][c];
  }
}

// ---------------------------------------------------------------------------
// Shared MFMA GEMM body (m97 structure): A bf16 [M][2048] x BT bf16 [N][2048]
// -> C fp32 [M][Nn].  128x128 tile, BK=32, 256 thr (4 waves 2x2), linear LDS,
// global_load_lds dwordx4 staging.
// ---------------------------------------------------------------------------
__device__ __forceinline__ void gemm128_gl(
    const bfu* __restrict__ A, const bfu* __restrict__ BT,
    float* __restrict__ C, const int Nn, const int m0, const int n0,
    bfu* As, bfu* Bs)
{
  const int tid = threadIdx.x;
  const int wave = tid >> 6, lane = tid & 63;
  const int wm = (wave >> 1) * 64, wn = (wave & 1) * 64;
  const int fm = lane & 15, quad = lane >> 4;
  const int sr = tid >> 2, skc = (tid & 3) * 8;  // staging row / k-col

  frag_cd acc[4][4];
#pragma unroll
  for (int i = 0; i < 4; ++i)
#pragma unroll
    for (int j = 0; j < 4; ++j) acc[i][j] = (frag_cd){0.f, 0.f, 0.f, 0.f};

  const bfu* Ag = A + (size_t)(m0 + sr) * 2048 + skc;
  const bfu* Bg = BT + (size_t)(n0 + sr) * 2048 + skc;
  bfu* Al = As + tid * 8;   // lane-linear: tid*16 bytes
  bfu* Bl = Bs + tid * 8;

  for (int k0 = 0; k0 < 2048; k0 += 32) {
    gl16(Ag + k0, Al);
    gl16(Ag + k0 + (size_t)64 * 2048, Al + 64 * 32);
    gl16(Bg + k0, Bl);
    gl16(Bg + k0 + (size_t)64 * 2048, Bl + 64 * 32);
    __syncthreads();  // compiler drains vmcnt before s_barrier
    frag_ab a[4], b[4];
#pragma unroll
    for (int im = 0; im < 4; ++im)
      a[im] = *(const frag_ab*)&As[(size_t)(wm + im * 16 + fm) * 32 + quad * 8];
#pragma unroll
    for (int in = 0; in < 4; ++in)
      b[in] = *(const frag_ab*)&Bs[(size_t)(wn + in * 16 + fm) * 32 + quad * 8];
#pragma unroll
    for (int im = 0; im < 4; ++im)
#pragma unroll
      for (int in = 0; in < 4; ++in)
        acc[im][in] = __builtin_amdgcn_mfma_f32_16x16x32_bf16(
            a[im], b[in], acc[im][in], 0, 0, 0);
    __syncthreads();
  }
#pragma unroll
  for (int im = 0; im < 4; ++im)
#pragma unroll
    for (int in = 0; in < 4; ++in) {
      const int n = n0 + wn + in * 16 + fm;
#pragma unroll
      for (int r = 0; r < 4; ++r) {
        const int m = m0 + wm + im * 16 + quad * 4 + r;
        C[(size_t)m * Nn + n] = acc[im][in][r];
      }
    }
}

// Fused Q/K/V projection: all three GEMMs in one 384-block dispatch.
__global__ __launch_bounds__(256) void gemm_qkv_k(
    const bfu* __restrict__ A, const bfu* __restrict__ BTq,
    const bfu* __restrict__ BTk, const bfu* __restrict__ BTv,
    float* __restrict__ Cq, float* __restrict__ Ck, float* __restrict__ Cv)
{
  __shared__ __align__(16) bfu As[128 * 32];
  __shared__ __align__(16) bfu Bs[128 * 32];
  int bx = blockIdx.x;
  const bfu* BT; float* C; int Nn;
  if (bx < 16)      { BT = BTq; C = Cq; Nn = 2048; }
  else if (bx < 20) { BT = BTk; C = Ck; Nn = 512; bx -= 16; }
  else              { BT = BTv; C = Cv; Nn = 512; bx -= 20; }
  gemm128_gl(A, BT, C, Nn, blockIdx.y * 128, bx * 128, As, Bs);
}

// Output projection GEMM.
__global__ __launch_bounds__(256) void gemm_wo_k(
    const bfu* __restrict__ A, const bfu* __restrict__ BT, float* __restrict__ C)
{
  __shared__ __align__(16) bfu As[128 * 32];
  __shared__ __align__(16) bfu Bs[128 * 32];
  gemm128_gl(A, BT, C, 2048, blockIdx.y * 128, blockIdx.x * 128, As, Bs);
}

// ---------------------------------------------------------------------------
// Per-row (64-wide) softmax of k -> kl, log_sigmoid(k)/16 -> gl, and
// k_bf = bf16(k) (pre-cast for the attention kernels, free ride on the read).
// ---------------------------------------------------------------------------
__global__ __launch_bounds__(256) void gates64_k(
    const float* __restrict__ kin, float* __restrict__ kl, float* __restrict__ gl,
    bfu* __restrict__ k_bf)
{
  const int r = blockIdx.x * 4 + (threadIdx.x >> 6);
  const int lane = threadIdx.x & 63;
  const size_t idx = (size_t)r * 64 + lane;
  const float x = kin[idx];
  k_bf[idx] = f2bf(x);
  float m = x;
#pragma unroll
  for (int o = 32; o > 0; o >>= 1) m = fmaxf(m, __shfl_xor(m, o, 64));
  const float e = __expf(x - m);
  float s = e;
#pragma unroll
  for (int o = 32; o > 0; o >>= 1) s += __shfl_xor(s, o, 64);
  kl[idx] = e / s;
  const float ls = fminf(x, 0.f) - log1pf(__expf(-fabsf(x)));
  gl[idx] = ls * 0.0625f;
}

// ---------------------------------------------------------------------------
// Per (b,hkv,chunk): triangular solves.  256 blocks.
// ---------------------------------------------------------------------------
__global__ __launch_bounds__(256) void chunk_prep_k(
    const float* __restrict__ kl, const float* __restrict__ v,
    const float* __restrict__ gl, float* __restrict__ u_out, float* __restrict__ w_out)
{
  __shared__ float KC[64][65];
  __shared__ float KB[64][65];
  __shared__ float VB[64][65];
  const int blk = blockIdx.x;
  const int c = blk & 15, bh = blk >> 4;
  const int hk = bh & 7, b = bh >> 3;
  const int tid = threadIdx.x;
  for (int x = tid; x < 4096; x += 256) {
    const int i = x >> 6, d = x & 63;
    const size_t src = ((size_t)(b * Nc + c * 64 + i) * 8 + hk) * 64 + d;
    const float kv = kl[src], g = gl[src], vv = v[src];
    KC[i][d] = kv; KB[i][d] = kv * g; VB[i][d] = vv * g;
  }
  __syncthreads();
  float Lreg[16];
#pragma unroll
  for (int e = 0; e < 16; ++e) {
    const int x = e * 256 + tid;
    const int i = x >> 6, j = x & 63;
    float acc = 0.f;
    if (j < i) {
      for (int d = 0; d < 64; ++d) acc += KB[i][d] * KC[j][d];
    }
    Lreg[e] = acc;
  }
  __syncthreads();
#pragma unroll
  for (int e = 0; e < 16; ++e) {
    const int x = e * 256 + tid;
    KC[x >> 6][x & 63] = Lreg[e];
  }
  __syncthreads();
  if (tid < 128) {
    const int d = tid & 63;
    float (*X)[65] = (tid < 64) ? VB : KB;
    for (int i = 1; i < 64; ++i) {
      float acc = X[i][d];
      for (int j = 0; j < i; ++j) acc -= KC[i][j] * X[j][d];
      X[i][d] = acc;
    }
  }
  __syncthreads();
  for (int x = tid; x < 4096; x += 256) {
    u_out[(size_t)blk * 4096 + x] = VB[x >> 6][x & 63];
    w_out[(size_t)blk * 4096 + x] = KB[x >> 6][x & 63];
  }
}

// ---------------------------------------------------------------------------
// Serial scan over chunks per (b,hkv).  16 blocks x 512 threads.
// ---------------------------------------------------------------------------
__global__ __launch_bounds__(512) void scan_k(
    const float* __restrict__ u_ps, const float* __restrict__ w_ps,
    const float* __restrict__ kl, float* __restrict__ u_p, float* __restrict__ S_pre)
{
  __shared__ float S[64][64];
  __shared__ float kw[64][64];
  __shared__ float kt[64][64];
  __shared__ float up[64][72];
  const int blk = blockIdx.x;
  const int hk = blk & 7, b = blk >> 3;
  const int t = threadIdx.x;
  const int row = t >> 3;
  const int c0 = (t & 7) * 8;
  for (int x = t; x < 4096; x += 512) S[x >> 6][x & 63] = 0.f;
  __syncthreads();
  for (int c = 0; c < 16; ++c) {
    const size_t cb = ((size_t)blk * 16 + c) * 4096;
    float upre[8];
    {
      const float* ug = u_ps + cb + row * 64 + c0;
#pragma unroll
      for (int j = 0; j < 8; ++j) upre[j] = ug[j];
    }
    for (int x = t; x < 4096; x += 512) {
      const int i = x >> 6, d = x & 63;
      S_pre[cb + x] = S[i][d];
      kw[i][d] = w_ps[cb + x];
      kt[i][d] = kl[((size_t)(b * Nc + c * 64 + i) * 8 + hk) * 64 + d];
    }
    __syncthreads();
    {
      float acc[8];
#pragma unroll
      for (int j = 0; j < 8; ++j) acc[j] = upre[j];
      for (int e = 0; e < 64; ++e) {
        const float wv = kw[row][e];
#pragma unroll
        for (int j = 0; j < 8; ++j) acc[j] -= wv * S[e][c0 + j];
      }
      float* upg = u_p + cb + row * 64 + c0;
#pragma unroll
      for (int j = 0; j < 8; ++j) { up[row][c0 + j] = acc[j]; upg[j] = acc[j]; }
    }
    __syncthreads();
    {
      float sacc[8];
#pragma unroll
      for (int j = 0; j < 8; ++j) sacc[j] = S[row][c0 + j];
      for (int i = 0; i < 64; ++i) {
        const float kv = kt[i][row];
#pragma unroll
        for (int j = 0; j < 8; ++j) sacc[j] += kv * up[i][c0 + j];
      }
#pragma unroll
      for (int j = 0; j < 8; ++j) S[row][c0 + j] = sacc[j];
    }
    __syncthreads();
  }
}

// ---------------------------------------------------------------------------
// o_lin per (b,h,chunk).  1024 blocks.
// ---------------------------------------------------------------------------
__global__ __launch_bounds__(256) void olin_k(
    const float* __restrict__ qraw, const float* __restrict__ kl,
    const float* __restrict__ upb, const float* __restrict__ S_pre,
    float* __restrict__ o_comb)
{
  __shared__ float Q[64][65];
  __shared__ __align__(16) float Bb[64][68];
  __shared__ float At[64][65];
  const int blk = blockIdx.x;
  const int c = blk & 15, bh = blk >> 4;
  const int h = bh & 31, b = bh >> 5, hk = h >> 2;
  const int tid = threadIdx.x;
  const int i = tid >> 2, d0 = (tid & 3) * 16;
  for (int x = tid; x < 4096; x += 256) {
    const int r = x >> 6, d = x & 63;
    Q[r][d] = qraw[((size_t)(b * Nc + c * 64 + r) * 32 + h) * 64 + d];
    Bb[r][d] = kl[((size_t)(b * Nc + c * 64 + r) * 8 + hk) * 64 + d];
  }
  __syncthreads();
  {
    float mx = -1e30f;
#pragma unroll
    for (int j = 0; j < 16; ++j) mx = fmaxf(mx, Q[i][d0 + j]);
#pragma unroll
    for (int o = 1; o < 4; o <<= 1) mx = fmaxf(mx, __shfl_xor(mx, o, 64));
    float ev[16];
    float sum = 0.f;
#pragma unroll
    for (int j = 0; j < 16; ++j) { ev[j] = __expf(Q[i][d0 + j] - mx); sum += ev[j]; }
#pragma unroll
    for (int o = 1; o < 4; o <<= 1) sum += __shfl_xor(sum, o, 64);
    const float inv = 1.f / sum;
#pragma unroll
    for (int j = 0; j < 16; ++j) Q[i][d0 + j] = ev[j] * inv;
  }
  {
    float a[16];
#pragma unroll
    for (int j = 0; j < 16; ++j) a[j] = 0.f;
    for (int d = 0; d < 64; ++d) {
      const float qv = Q[i][d];
#pragma unroll
      for (int j = 0; j < 16; ++j) a[j] += qv * Bb[d0 + j][d];
    }
#pragma unroll
    for (int j = 0; j < 16; ++j) At[i][d0 + j] = (d0 + j <= i) ? a[j] : 0.f;
  }
  __syncthreads();
  const size_t cb = ((size_t)(b * 8 + hk) * 16 + c) * 4096;
  for (int x = tid; x < 4096; x += 256) Bb[x >> 6][x & 63] = S_pre[cb + x];
  __syncthreads();
  float o[16];
#pragma unroll
  for (int j = 0; j < 16; ++j) o[j] = 0.f;
  for (int e = 0; e < 64; ++e) {
    const float qv = Q[i][e];
#pragma unroll
    for (int j = 0; j < 16; ++j) o[j] += qv * Bb[e][d0 + j];
  }
  __syncthreads();
  for (int x = tid; x < 4096; x += 256) Bb[x >> 6][x & 63] = upb[cb + x];
  __syncthreads();
  for (int j2 = 0; j2 < 64; ++j2) {
    const float av = At[i][j2];
#pragma unroll
    for (int j = 0; j < 16; ++j) o[j] += av * Bb[j2][d0 + j];
  }
  float* oc = o_comb + ((size_t)(b * Nc + c * 64 + i) * 32 + h) * 64 + d0;
#pragma unroll
  for (int j = 0; j < 16; ++j) oc[j] = 0.5f * o[j];
}

// ---------------------------------------------------------------------------
// Tile-copy helpers: 64x64 bf16 tile global -> LDS [row][LDK], 2 uint4/thread.
// ---------------------------------------------------------------------------
template <int LDK>
__device__ __forceinline__ void stage_tile(
    const bfu* __restrict__ g, size_t row_stride, bfu* dst, int tid)
{
  const int xr = tid >> 3;         // 0..31
  const int xc = (tid & 7) * 8;    // 0,8,..,56
#pragma unroll
  for (int hh = 0; hh < 2; ++hh) {
    const int row = xr + hh * 32;
    *(uint4*)&dst[(size_t)row * LDK + xc] =
        *(const uint4*)(g + (size_t)row * row_stride + xc);
  }
}

// ---------------------------------------------------------------------------
// Base attention pass A (MFMA): online m,l only.  Inputs pre-cast bf16.
// S^T orientation: A = K (m=j), B = Q (n=i), k = d.  1024 blocks x 256 thr.
// ---------------------------------------------------------------------------
__global__ __launch_bounds__(256) void ml_mfma_k(
    const bfu* __restrict__ qbf, const bfu* __restrict__ kbf,
    float* __restrict__ mbuf, float* __restrict__ lbuf)
{
  constexpr int LDK = 72;
  __shared__ __align__(16) bfu Qt[64 * LDK];  // [i][d]
  __shared__ __align__(16) bfu Kt[64 * LDK];  // [j][d]
  __shared__ float mred[4][64];
  __shared__ float lred[4][64];
  const int blk = blockIdx.x;
  const int ib = blk & 15, bh = blk >> 4;
  const int h = bh & 31, b = bh >> 5, hk = h >> 2;
  const int tid = threadIdx.x;
  const int wave = tid >> 6, lane = tid & 63;
  const int fm = lane & 15, quad = lane >> 4;
  const int wj = wave * 16;

  // stage Qt [i][d] bf16 (rows stride 32*64 in qbf)
  stage_tile<LDK>(qbf + ((size_t)(b * Nc + ib * 64) * 32 + h) * 64,
                  (size_t)32 * 64, Qt, tid);
  __syncthreads();
  frag_ab qb[4][2];
#pragma unroll
  for (int in = 0; in < 4; ++in)
#pragma unroll
    for (int kk = 0; kk < 2; ++kk)
      qb[in][kk] = *(const frag_ab*)&Qt[(size_t)(in * 16 + fm) * LDK + kk * 32 + quad * 8];

  float m[4], l[4];
#pragma unroll
  for (int in = 0; in < 4; ++in) { m[in] = -1e30f; l[in] = 0.f; }

  for (int jt = 0; jt <= ib; ++jt) {
    __syncthreads();
    stage_tile<LDK>(kbf + ((size_t)(b * Nc + jt * 64) * 8 + hk) * 64,
                    (size_t)8 * 64, Kt, tid);
    __syncthreads();
    frag_ab ka[2];
    ka[0] = *(const frag_ab*)&Kt[(size_t)(wj + fm) * LDK + quad * 8];
    ka[1] = *(const frag_ab*)&Kt[(size_t)(wj + fm) * LDK + 32 + quad * 8];
    const bool diag = (jt == ib);
#pragma unroll
    for (int in = 0; in < 4; ++in) {
      frag_cd acc = (frag_cd){0.f, 0.f, 0.f, 0.f};
      acc = __builtin_amdgcn_mfma_f32_16x16x32_bf16(ka[0], qb[in][0], acc, 0, 0, 0);
      acc = __builtin_amdgcn_mfma_f32_16x16x32_bf16(ka[1], qb[in][1], acc, 0, 0, 0);
      const int iloc = in * 16 + fm;
      float sv[4];
      bool vd[4];
      float tm = -1e30f;
#pragma unroll
      for (int r = 0; r < 4; ++r) {
        const int jloc = wj + quad * 4 + r;
        vd[r] = !diag || (jloc <= iloc);
        sv[r] = acc[r] * 0.125f;
        if (vd[r]) tm = fmaxf(tm, sv[r]);
      }
      const float mn = fmaxf(m[in], tm);
      float lsum = 0.f;
#pragma unroll
      for (int r = 0; r < 4; ++r)
        if (vd[r]) lsum += __expf(sv[r] - mn);
      l[in] = l[in] * __expf(m[in] - mn) + lsum;  // l==0 when m==-1e30, safe
      m[in] = mn;
    }
  }
#pragma unroll
  for (int in = 0; in < 4; ++in) {
    float mm = m[in], ll = l[in];
#pragma unroll
    for (int off = 16; off < 64; off <<= 1) {
      const float mo = __shfl_xor(mm, off, 64);
      const float lo = __shfl_xor(ll, off, 64);
      const float mn = fmaxf(mm, mo);
      ll = ll * __expf(mm - mn) + lo * __expf(mo - mn);
      mm = mn;
    }
    if (quad == 0) { mred[wave][in * 16 + fm] = mm; lred[wave][in * 16 + fm] = ll; }
  }
  __syncthreads();
  if (tid < 64) {
    float M = -1e30f;
#pragma unroll
    for (int w = 0; w < 4; ++w) M = fmaxf(M, mred[w][tid]);
    float L = 0.f;
#pragma unroll
    for (int w = 0; w < 4; ++w) L += lred[w][tid] * __expf(mred[w][tid] - M);
    const size_t rowi = (size_t)(b * 32 + h) * 1024 + ib * 64 + tid;
    mbuf[rowi] = M;
    lbuf[rowi] = L;
  }
}

// ---------------------------------------------------------------------------
// Base attention pass B (MFMA): recompute scores, p = exp(s-m)/l -> attn,
// PV via MFMA.  Inputs pre-cast bf16 (K) and pre-transposed bf16 (Vt).
// Writes oc_bf = bf16(o_comb + 0.5*o_base) directly.  1024 blocks x 256 thr.
// ---------------------------------------------------------------------------
__global__ __launch_bounds__(256) void pv_mfma_k(
    const bfu* __restrict__ qbf, const bfu* __restrict__ kbf,
    const bfu* __restrict__ vtbf, const float* __restrict__ mbuf,
    const float* __restrict__ lbuf, float* __restrict__ attn,
    const float* __restrict__ o_comb, bfu* __restrict__ oc_bf)
{
  constexpr int LDK = 72;
  __shared__ __align__(16) bfu Qt[64 * LDK];    // [i][d]
  __shared__ __align__(16) bfu Kt[64 * LDK];    // [j][d]
  __shared__ __align__(16) bfu Vt[64 * LDK];    // [dv][j]
  __shared__ __align__(16) bfu Pmat[64 * LDK];  // [i][j]
  const int blk = blockIdx.x;
  const int ib = blk & 15, bh = blk >> 4;
  const int h = bh & 31, b = bh >> 5, hk = h >> 2;
  const int tid = threadIdx.x;
  const int wave = tid >> 6, lane = tid & 63;
  const int fm = lane & 15, quad = lane >> 4;
  const int wj = wave * 16;   // score phase: wave's j slice
  const int im0 = wave * 16;  // PV phase: wave's i slice

  stage_tile<LDK>(qbf + ((size_t)(b * Nc + ib * 64) * 32 + h) * 64,
                  (size_t)32 * 64, Qt, tid);
  __syncthreads();
  frag_ab qb[4][2];
#pragma unroll
  for (int in = 0; in < 4; ++in)
#pragma unroll
    for (int kk = 0; kk < 2; ++kk)
      qb[in][kk] = *(const frag_ab*)&Qt[(size_t)(in * 16 + fm) * LDK + kk * 32 + quad * 8];

  float mi[4], il[4];
#pragma unroll
  for (int in = 0; in < 4; ++in) {
    const size_t rowi = (size_t)(b * 32 + h) * 1024 + ib * 64 + in * 16 + fm;
    mi[in] = mbuf[rowi];
    il[in] = 1.f / lbuf[rowi];
  }

  float* arow0 = attn + ((size_t)(b * 32 + h) * 1024 + ib * 64) * 1024;

  frag_cd o[4];
#pragma unroll
  for (int in = 0; in < 4; ++in) o[in] = (frag_cd){0.f, 0.f, 0.f, 0.f};

  for (int jt = 0; jt <= ib; ++jt) {
    __syncthreads();  // protect prev iter's Vt/Pmat reads
    stage_tile<LDK>(kbf + ((size_t)(b * Nc + jt * 64) * 8 + hk) * 64,
                    (size_t)8 * 64, Kt, tid);
    stage_tile<LDK>(vtbf + (size_t)(b * 8 + hk) * 64 * 1024 + jt * 64,
                    (size_t)1024, Vt, tid);
    __syncthreads();
    frag_ab ka[2];
    ka[0] = *(const frag_ab*)&Kt[(size_t)(wj + fm) * LDK + quad * 8];
    ka[1] = *(const frag_ab*)&Kt[(size_t)(wj + fm) * LDK + 32 + quad * 8];
    const bool diag = (jt == ib);
#pragma unroll
    for (int in = 0; in < 4; ++in) {
      frag_cd acc = (frag_cd){0.f, 0.f, 0.f, 0.f};
      acc = __builtin_amdgcn_mfma_f32_16x16x32_bf16(ka[0], qb[in][0], acc, 0, 0, 0);
      acc = __builtin_amdgcn_mfma_f32_16x16x32_bf16(ka[1], qb[in][1], acc, 0, 0, 0);
      const int iloc = in * 16 + fm;
      float p[4];
#pragma unroll
      for (int r = 0; r < 4; ++r) {
        const int jloc = wj + quad * 4 + r;
        const bool vdr = !diag || (jloc <= iloc);
        p[r] = vdr ? __expf(acc[r] * 0.125f - mi[in]) * il[in] : 0.f;
      }
      *(float4*)(arow0 + (size_t)iloc * 1024 + jt * 64 + wj + quad * 4) =
          make_float4(p[0], p[1], p[2], p[3]);
      ushort4 w;
      w.x = f2bf(p[0]); w.y = f2bf(p[1]); w.z = f2bf(p[2]); w.w = f2bf(p[3]);
      *(ushort4*)&Pmat[(size_t)iloc * LDK + wj + quad * 4] = w;
    }
    __syncthreads();
    frag_ab pa[2];
    pa[0] = *(const frag_ab*)&Pmat[(size_t)(im0 + fm) * LDK + quad * 8];
    pa[1] = *(const frag_ab*)&Pmat[(size_t)(im0 + fm) * LDK + 32 + quad * 8];
#pragma unroll
    for (int in = 0; in < 4; ++in) {
      frag_ab vb0 = *(const frag_ab*)&Vt[(size_t)(in * 16 + fm) * LDK + quad * 8];
      frag_ab vb1 = *(const frag_ab*)&Vt[(size_t)(in * 16 + fm) * LDK + 32 + quad * 8];
      o[in] = __builtin_amdgcn_mfma_f32_16x16x32_bf16(pa[0], vb0, o[in], 0, 0, 0);
      o[in] = __builtin_amdgcn_mfma_f32_16x16x32_bf16(pa[1], vb1, o[in], 0, 0, 0);
    }
  }
  // zero-fill non-causal tiles of attn
  for (int jt2 = ib + 1; jt2 < 16; ++jt2) {
    const float4 z = make_float4(0.f, 0.f, 0.f, 0.f);
    for (int x = tid; x < 1024; x += 256) {
      const int row = x >> 4, c4 = (x & 15) * 4;
      *(float4*)(arow0 + (size_t)row * 1024 + jt2 * 64 + c4) = z;
    }
  }
  // oc_bf = bf16(o_comb + 0.5*o)
#pragma unroll
  for (int in = 0; in < 4; ++in)
#pragma unroll
    for (int r = 0; r < 4; ++r) {
      const int i = im0 + quad * 4 + r;
      const size_t idx = ((size_t)(b * Nc + ib * 64 + i) * 32 + h) * 64 + in * 16 + fm;
      oc_bf[idx] = f2bf(o_comb[idx] + 0.5f * o[in][r]);
    }
}

// ---------------------------------------------------------------------------
extern "C" void kernel_launch(void* const* d_in, const int* in_sizes, int n_in,
                              void* d_out, int out_size, void* d_ws, size_t ws_size,
                              hipStream_t stream) {
  const float* hs = (const float*)d_in[0];
  const float* Wq = (const float*)d_in[1];
  const float* Wk = (const float*)d_in[2];
  const float* Wv = (const float*)d_in[3];
  const float* Wo = (const float*)d_in[4];
  float* out = (float*)d_out;                      // [B,N,HID]
  float* attn = out + (size_t)Bc * Nc * HIDc;      // [B,H,N,N]

  float* ws = (float*)d_ws;
  float* q_raw  = ws;                     // 4,194,304 f32
  float* k_raw  = q_raw + 4194304;        // 1,048,576
  float* v_raw  = k_raw + 1048576;        // 1,048,576
  float* kl     = v_raw + 1048576;        // 1,048,576
  float* gl     = kl + 1048576;           // 1,048,576
  float* u_ps   = gl + 1048576;           // 2,097,152
  float* w_ps   = u_ps + 2097152;         // 2,097,152
  float* upb    = w_ps + 2097152;         // 2,097,152
  float* S_pre  = upb + 2097152;          // 2,097,152
  float* o_comb = S_pre + 2097152;        // 4,194,304
  float* mbuf   = o_comb + 4194304;       // 65,536
  float* lbuf   = mbuf + 65536;           // 65,536
  bfu* bstart = (bfu*)(lbuf + 65536);
  bfu* hs_bf  = bstart;                   // 4,194,304 bf16
  bfu* WqT    = hs_bf + 4194304;          // 4,194,304
  bfu* WkT    = WqT + 4194304;            // 1,048,576
  bfu* WvT    = WkT + 1048576;            // 1,048,576
  bfu* WoT    = WvT + 1048576;            // 4,194,304
  bfu* oc_bf  = WoT + 4194304;            // 4,194,304
  // Aliases of regions dead after gemm_qkv_k (stream-ordered, safe):
  bfu* q_bf   = hs_bf;                    // 4,194,304 bf16 (aliases hs_bf)
  bfu* k_bf   = WqT;                      // 1,048,576 bf16 (aliases WqT)
  bfu* vt_bf  = WqT + 1048576;            // 1,048,576 bf16 (aliases WqT+1M)

  // Casts / weight transposes
  cast_bf16_k<<<4096, 256, 0, stream>>>(hs, hs_bf);
  transpose_cast_k<<<dim3(64, 64), 256, 0, stream>>>(Wq, WqT, 2048, 2048);
  transpose_cast_k<<<dim3(16, 64), 256, 0, stream>>>(Wk, WkT, 2048, 512);
  transpose_cast_k<<<dim3(16, 64), 256, 0, stream>>>(Wv, WvT, 2048, 512);
  transpose_cast_k<<<dim3(64, 64), 256, 0, stream>>>(Wo, WoT, 2048, 2048);
  // Fused Q/K/V projection (bf16 MFMA, global_load_lds staging, 384 blocks)
  gemm_qkv_k<<<dim3(24, 16), 256, 0, stream>>>(hs_bf, WqT, WkT, WvT,
                                               q_raw, k_raw, v_raw);
  // Pre-cast attention inputs (q_bf aliases hs_bf; k_bf/vt_bf alias WqT —
  // both dead after gemm_qkv_k above).
  cast_bf16_k<<<4096, 256, 0, stream>>>(q_raw, q_bf);
  gates64_k<<<4096, 256, 0, stream>>>(k_raw, kl, gl, k_bf);
  transpose_v_k<<<256, 256, 0, stream>>>(v_raw, vt_bf);
  // Delta-rule
  chunk_prep_k<<<256, 256, 0, stream>>>(kl, v_raw, gl, u_ps, w_ps);
  scan_k<<<16, 512, 0, stream>>>(u_ps, w_ps, kl, upb, S_pre);
  // Linear-attention output (writes o_comb = 0.5*o_lin)
  olin_k<<<1024, 256, 0, stream>>>(q_raw, kl, upb, S_pre, o_comb);
  // Base causal attention: MFMA m,l pass then fused p/attn-write/PV pass
  ml_mfma_k<<<1024, 256, 0, stream>>>(q_bf, k_bf, mbuf, lbuf);
  pv_mfma_k<<<1024, 256, 0, stream>>>(q_bf, k_bf, vt_bf, mbuf, lbuf, attn,
                                      o_comb, oc_bf);
  // Output projection (reads bf16 written by pv_mfma_k)
  gemm_wo_k<<<dim3(16, 16), 256, 0, stream>>>(oc_bf, WoT, out);
}

// Round 4
// 734.972 us; speedup vs baseline: 1.0565x; 1.0565x over previous
//
#include <hip/hip_runtime.h>
#include <hip/hip_bf16.h>

// Problem constants
constexpr int Bc = 2, Nc = 1024, HIDc = 2048, Hc = 32, Dc = 64, HKVc = 8, NCc = 16;

typedef unsigned short bfu;  // raw bf16 bits
typedef __attribute__((ext_vector_type(8))) short frag_ab;  // 8 bf16 (4 VGPRs)
typedef __attribute__((ext_vector_type(4))) float frag_cd;  // 4 fp32 acc

__device__ __forceinline__ bfu f2bf(float f) {
  unsigned int u = __float_as_uint(f);
  unsigned int r = u + 0x7fffu + ((u >> 16) & 1u);  // RNE
  return (bfu)(r >> 16);
}
__device__ __forceinline__ ushort4 pack4(float4 v) {
  ushort4 r; r.x = f2bf(v.x); r.y = f2bf(v.y); r.z = f2bf(v.z); r.w = f2bf(v.w);
  return r;
}

// async global->LDS, 16B per lane (m97 pattern: lane-linear staging layout)
__device__ __forceinline__ void gl16(const bfu* g, bfu* l) {
  __builtin_amdgcn_global_load_lds(
      (const __attribute__((address_space(1))) void*)g,
      (__attribute__((address_space(3))) void*)l, 16, 0, 0);
}

// ---------------------------------------------------------------------------
// Flat cast fp32 -> bf16 (4 elements/thread)
// ---------------------------------------------------------------------------
__global__ __launch_bounds__(256) void cast_bf16_k(
    const float* __restrict__ in, bfu* __restrict__ out)
{
  const size_t i = ((size_t)blockIdx.x * 256 + threadIdx.x) * 4;
  *(ushort4*)(out + i) = pack4(*(const float4*)(in + i));
}

// ---------------------------------------------------------------------------
// Transpose + cast: W fp32 [K][N] -> WT bf16 [N][K].  32x32 tiles, 256 thr.
// ---------------------------------------------------------------------------
__global__ __launch_bounds__(256) void transpose_cast_k(
    const float* __restrict__ W, bfu* __restrict__ WT, int K, int N)
{
  __shared__ float t[32][33];
  const int bn = blockIdx.x * 32, bk = blockIdx.y * 32;
  const int x = threadIdx.x & 31, y = threadIdx.x >> 5;  // 32x8
#pragma unroll
  for (int i = 0; i < 32; i += 8)
    t[y + i][x] = W[(size_t)(bk + y + i) * N + bn + x];
  __syncthreads();
#pragma unroll
  for (int i = 0; i < 32; i += 8)
    WT[(size_t)(bn + y + i) * K + bk + x] = f2bf(t[x][y + i]);
}

// ---------------------------------------------------------------------------
// V transpose + cast: v fp32 [b,n,hk,dv] -> vt bf16 [b,hk,dv,n].  256 blocks.
// ---------------------------------------------------------------------------
__global__ __launch_bounds__(256) void transpose_v_k(
    const float* __restrict__ v, bfu* __restrict__ vt)
{
  __shared__ __align__(16) bfu T[64][72];
  const int blk = blockIdx.x;
  const int nt = blk & 15, bh = blk >> 4;  // n-tile, b*8+hk
  const int hk = bh & 7, b = bh >> 3;
  const int tid = threadIdx.x;
  const int n = tid >> 2, dv0 = (tid & 3) * 16;
  const float* src = v + ((size_t)(b * Nc + nt * 64 + n) * 8 + hk) * 64 + dv0;
#pragma unroll
  for (int e = 0; e < 16; ++e) T[dv0 + e][n] = f2bf(src[e]);
  __syncthreads();
  const int r = tid >> 3, c = (tid & 7) * 8;
#pragma unroll
  for (int hh = 0; hh < 2; ++hh) {
    const int dv = r + hh * 32;
    *(uint4*)(vt + ((size_t)(bh * 64 + dv)) * 1024 + nt * 64 + c) =
        *(const uint4*)&T[dv][c];
  }
}

// ---------------------------------------------------------------------------
// Shared MFMA GEMM body (m97 structure): A bf16 [M][2048] x BT bf16 [N][2048]
// -> C fp32 [M][Nn].  128x128 tile, BK=32, 256 thr (4 waves 2x2), linear LDS,
// global_load_lds dwordx4 staging.
// ---------------------------------------------------------------------------
__device__ __forceinline__ void gemm128_gl(
    const bfu* __restrict__ A, const bfu* __restrict__ BT,
    float* __restrict__ C, const int Nn, const int m0, const int n0,
    bfu* As, bfu* Bs)
{
  const int tid = threadIdx.x;
  const int wave = tid >> 6, lane = tid & 63;
  const int wm = (wave >> 1) * 64, wn = (wave & 1) * 64;
  const int fm = lane & 15, quad = lane >> 4;
  const int sr = tid >> 2, skc = (tid & 3) * 8;  // staging row / k-col

  frag_cd acc[4][4];
#pragma unroll
  for (int i = 0; i < 4; ++i)
#pragma unroll
    for (int j = 0; j < 4; ++j) acc[i][j] = (frag_cd){0.f, 0.f, 0.f, 0.f};

  const bfu* Ag = A + (size_t)(m0 + sr) * 2048 + skc;
  const bfu* Bg = BT + (size_t)(n0 + sr) * 2048 + skc;
  bfu* Al = As + tid * 8;   // lane-linear: tid*16 bytes
  bfu* Bl = Bs + tid * 8;

  for (int k0 = 0; k0 < 2048; k0 += 32) {
    gl16(Ag + k0, Al);
    gl16(Ag + k0 + (size_t)64 * 2048, Al + 64 * 32);
    gl16(Bg + k0, Bl);
    gl16(Bg + k0 + (size_t)64 * 2048, Bl + 64 * 32);
    __syncthreads();  // compiler drains vmcnt before s_barrier
    frag_ab a[4], b[4];
#pragma unroll
    for (int im = 0; im < 4; ++im)
      a[im] = *(const frag_ab*)&As[(size_t)(wm + im * 16 + fm) * 32 + quad * 8];
#pragma unroll
    for (int in = 0; in < 4; ++in)
      b[in] = *(const frag_ab*)&Bs[(size_t)(wn + in * 16 + fm) * 32 + quad * 8];
#pragma unroll
    for (int im = 0; im < 4; ++im)
#pragma unroll
      for (int in = 0; in < 4; ++in)
        acc[im][in] = __builtin_amdgcn_mfma_f32_16x16x32_bf16(
            a[im], b[in], acc[im][in], 0, 0, 0);
    __syncthreads();
  }
#pragma unroll
  for (int im = 0; im < 4; ++im)
#pragma unroll
    for (int in = 0; in < 4; ++in) {
      const int n = n0 + wn + in * 16 + fm;
#pragma unroll
      for (int r = 0; r < 4; ++r) {
        const int m = m0 + wm + im * 16 + quad * 4 + r;
        C[(size_t)m * Nn + n] = acc[im][in][r];
      }
    }
}

// Fused Q/K/V projection: all three GEMMs in one 384-block dispatch.
__global__ __launch_bounds__(256) void gemm_qkv_k(
    const bfu* __restrict__ A, const bfu* __restrict__ BTq,
    const bfu* __restrict__ BTk, const bfu* __restrict__ BTv,
    float* __restrict__ Cq, float* __restrict__ Ck, float* __restrict__ Cv)
{
  __shared__ __align__(16) bfu As[128 * 32];
  __shared__ __align__(16) bfu Bs[128 * 32];
  int bx = blockIdx.x;
  const bfu* BT; float* C; int Nn;
  if (bx < 16)      { BT = BTq; C = Cq; Nn = 2048; }
  else if (bx < 20) { BT = BTk; C = Ck; Nn = 512; bx -= 16; }
  else              { BT = BTv; C = Cv; Nn = 512; bx -= 20; }
  gemm128_gl(A, BT, C, Nn, blockIdx.y * 128, bx * 128, As, Bs);
}

// Output projection GEMM.
__global__ __launch_bounds__(256) void gemm_wo_k(
    const bfu* __restrict__ A, const bfu* __restrict__ BT, float* __restrict__ C)
{
  __shared__ __align__(16) bfu As[128 * 32];
  __shared__ __align__(16) bfu Bs[128 * 32];
  gemm128_gl(A, BT, C, 2048, blockIdx.y * 128, blockIdx.x * 128, As, Bs);
}

// ---------------------------------------------------------------------------
// Per-row (64-wide) softmax of k -> kl, log_sigmoid(k)/16 -> gl, and
// k_bf = bf16(k) (pre-cast for the attention kernels).
// ---------------------------------------------------------------------------
__global__ __launch_bounds__(256) void gates64_k(
    const float* __restrict__ kin, float* __restrict__ kl, float* __restrict__ gl,
    bfu* __restrict__ k_bf)
{
  const int r = blockIdx.x * 4 + (threadIdx.x >> 6);
  const int lane = threadIdx.x & 63;
  const size_t idx = (size_t)r * 64 + lane;
  const float x = kin[idx];
  k_bf[idx] = f2bf(x);
  float m = x;
#pragma unroll
  for (int o = 32; o > 0; o >>= 1) m = fmaxf(m, __shfl_xor(m, o, 64));
  const float e = __expf(x - m);
  float s = e;
#pragma unroll
  for (int o = 32; o > 0; o >>= 1) s += __shfl_xor(s, o, 64);
  kl[idx] = e / s;
  const float ls = fminf(x, 0.f) - log1pf(__expf(-fabsf(x)));
  gl[idx] = ls * 0.0625f;
}

// ---------------------------------------------------------------------------
// Per (b,hkv,chunk): triangular solves.  256 blocks.
// KC holds kl TRANSPOSED ([d][i], pad 68 for aligned b128 reads) during the
// L-matmul, then is overwritten with L for the solve.
// ---------------------------------------------------------------------------
__global__ __launch_bounds__(256) void chunk_prep_k(
    const float* __restrict__ kl, const float* __restrict__ v,
    const float* __restrict__ gl, float* __restrict__ u_out, float* __restrict__ w_out)
{
  __shared__ __align__(16) float KC[64][68];  // klT, then L
  __shared__ float KB[64][65];
  __shared__ float VB[64][65];
  const int blk = blockIdx.x;
  const int c = blk & 15, bh = blk >> 4;
  const int hk = bh & 7, b = bh >> 3;
  const int tid = threadIdx.x;
  for (int x = tid; x < 4096; x += 256) {
    const int i = x >> 6, d = x & 63;
    const size_t src = ((size_t)(b * Nc + c * 64 + i) * 8 + hk) * 64 + d;
    const float kv = kl[src], g = gl[src], vv = v[src];
    KC[d][i] = kv; KB[i][d] = kv * g; VB[i][d] = vv * g;
  }
  __syncthreads();
  // L[i][j] = sum_d KB[i][d] * kl[j][d], strictly lower.  Thread: (i, 16 j's).
  const int li = tid >> 2, j0 = (tid & 3) * 16;
  float acc[16];
#pragma unroll
  for (int jj = 0; jj < 16; ++jj) acc[jj] = 0.f;
  for (int d = 0; d < 64; ++d) {
    const float kb = KB[li][d];
    const float4 c0v = *(const float4*)&KC[d][j0];
    const float4 c1v = *(const float4*)&KC[d][j0 + 4];
    const float4 c2v = *(const float4*)&KC[d][j0 + 8];
    const float4 c3v = *(const float4*)&KC[d][j0 + 12];
    acc[0] += kb * c0v.x;  acc[1] += kb * c0v.y;  acc[2] += kb * c0v.z;  acc[3] += kb * c0v.w;
    acc[4] += kb * c1v.x;  acc[5] += kb * c1v.y;  acc[6] += kb * c1v.z;  acc[7] += kb * c1v.w;
    acc[8] += kb * c2v.x;  acc[9] += kb * c2v.y;  acc[10] += kb * c2v.z; acc[11] += kb * c2v.w;
    acc[12] += kb * c3v.x; acc[13] += kb * c3v.y; acc[14] += kb * c3v.z; acc[15] += kb * c3v.w;
  }
  __syncthreads();
#pragma unroll
  for (int jj = 0; jj < 16; ++jj)
    KC[li][j0 + jj] = (j0 + jj < li) ? acc[jj] : 0.f;
  __syncthreads();
  if (tid < 128) {
    const int d = tid & 63;
    float (*X)[65] = (tid < 64) ? VB : KB;
    for (int i = 1; i < 64; ++i) {
      float a2 = X[i][d];
      for (int j = 0; j < i; ++j) a2 -= KC[i][j] * X[j][d];
      X[i][d] = a2;
    }
  }
  __syncthreads();
  for (int x = tid; x < 4096; x += 256) {
    u_out[(size_t)blk * 4096 + x] = VB[x >> 6][x & 63];
    w_out[(size_t)blk * 4096 + x] = KB[x >> 6][x & 63];
  }
}

// ---------------------------------------------------------------------------
// Serial scan over chunks per (b,hkv).  16 blocks x 512 threads.
// All LDS tiles padded to [64][68] (bank-conflict-free, 16B-aligned rows);
// phase-1 e-loop unrolled x4 with b128 kw loads; vectorized up/u_p writes.
// ---------------------------------------------------------------------------
__global__ __launch_bounds__(512) void scan_k(
    const float* __restrict__ u_ps, const float* __restrict__ w_ps,
    const float* __restrict__ kl, float* __restrict__ u_p, float* __restrict__ S_pre)
{
  __shared__ __align__(16) float S[64][68];
  __shared__ __align__(16) float kw[64][68];
  __shared__ __align__(16) float kt[64][68];
  __shared__ __align__(16) float up[64][68];
  const int blk = blockIdx.x;
  const int hk = blk & 7, b = blk >> 3;
  const int t = threadIdx.x;
  const int row = t >> 3;
  const int c0 = (t & 7) * 8;
  for (int x = t; x < 4096; x += 512) S[x >> 6][x & 63] = 0.f;
  __syncthreads();
  for (int c = 0; c < 16; ++c) {
    const size_t cb = ((size_t)blk * 16 + c) * 4096;
    float upre[8];
    {
      const float* ug = u_ps + cb + row * 64 + c0;
#pragma unroll
      for (int j = 0; j < 8; ++j) upre[j] = ug[j];
    }
    for (int x = t; x < 4096; x += 512) {
      const int i = x >> 6, d = x & 63;
      S_pre[cb + x] = S[i][d];
      kw[i][d] = w_ps[cb + x];
      kt[i][d] = kl[((size_t)(b * Nc + c * 64 + i) * 8 + hk) * 64 + d];
    }
    __syncthreads();
    {
      float acc[8];
#pragma unroll
      for (int j = 0; j < 8; ++j) acc[j] = upre[j];
      for (int e4 = 0; e4 < 64; e4 += 4) {
        const float4 wv4 = *(const float4*)&kw[row][e4];
#pragma unroll
        for (int ee = 0; ee < 4; ++ee) {
          const float wv = ((const float*)&wv4)[ee];
          const float4 s0 = *(const float4*)&S[e4 + ee][c0];
          const float4 s1 = *(const float4*)&S[e4 + ee][c0 + 4];
          acc[0] -= wv * s0.x; acc[1] -= wv * s0.y;
          acc[2] -= wv * s0.z; acc[3] -= wv * s0.w;
          acc[4] -= wv * s1.x; acc[5] -= wv * s1.y;
          acc[6] -= wv * s1.z; acc[7] -= wv * s1.w;
        }
      }
      const float4 o0 = make_float4(acc[0], acc[1], acc[2], acc[3]);
      const float4 o1 = make_float4(acc[4], acc[5], acc[6], acc[7]);
      *(float4*)&up[row][c0] = o0;
      *(float4*)&up[row][c0 + 4] = o1;
      float* upg = u_p + cb + row * 64 + c0;
      *(float4*)upg = o0;
      *(float4*)(upg + 4) = o1;
    }
    __syncthreads();
    {
      float sacc[8];
      {
        const float4 s0 = *(const float4*)&S[row][c0];
        const float4 s1 = *(const float4*)&S[row][c0 + 4];
        sacc[0] = s0.x; sacc[1] = s0.y; sacc[2] = s0.z; sacc[3] = s0.w;
        sacc[4] = s1.x; sacc[5] = s1.y; sacc[6] = s1.z; sacc[7] = s1.w;
      }
      for (int i = 0; i < 64; ++i) {
        const float kv = kt[i][row];
        const float4 u0 = *(const float4*)&up[i][c0];
        const float4 u1 = *(const float4*)&up[i][c0 + 4];
        sacc[0] += kv * u0.x; sacc[1] += kv * u0.y;
        sacc[2] += kv * u0.z; sacc[3] += kv * u0.w;
        sacc[4] += kv * u1.x; sacc[5] += kv * u1.y;
        sacc[6] += kv * u1.z; sacc[7] += kv * u1.w;
      }
      *(float4*)&S[row][c0] = make_float4(sacc[0], sacc[1], sacc[2], sacc[3]);
      *(float4*)&S[row][c0 + 4] = make_float4(sacc[4], sacc[5], sacc[6], sacc[7]);
    }
    __syncthreads();
  }
}

// ---------------------------------------------------------------------------
// o_lin per (b,h,chunk).  1024 blocks.
// Bb first holds kl TRANSPOSED ([d][r]) so matmul-1 reads are b128; then
// reused for S_pre and upb tiles as before.
// ---------------------------------------------------------------------------
__global__ __launch_bounds__(256) void olin_k(
    const float* __restrict__ qraw, const float* __restrict__ kl,
    const float* __restrict__ upb, const float* __restrict__ S_pre,
    float* __restrict__ o_comb)
{
  __shared__ float Q[64][65];
  __shared__ __align__(16) float Bb[64][68];
  __shared__ float At[64][65];
  const int blk = blockIdx.x;
  const int c = blk & 15, bh = blk >> 4;
  const int h = bh & 31, b = bh >> 5, hk = h >> 2;
  const int tid = threadIdx.x;
  const int i = tid >> 2, d0 = (tid & 3) * 16;
  for (int x = tid; x < 4096; x += 256) {
    const int r = x >> 6, d = x & 63;
    Q[r][d] = qraw[((size_t)(b * Nc + c * 64 + r) * 32 + h) * 64 + d];
    Bb[d][r] = kl[((size_t)(b * Nc + c * 64 + r) * 8 + hk) * 64 + d];  // klT
  }
  __syncthreads();
  {
    float mx = -1e30f;
#pragma unroll
    for (int j = 0; j < 16; ++j) mx = fmaxf(mx, Q[i][d0 + j]);
#pragma unroll
    for (int o = 1; o < 4; o <<= 1) mx = fmaxf(mx, __shfl_xor(mx, o, 64));
    float ev[16];
    float sum = 0.f;
#pragma unroll
    for (int j = 0; j < 16; ++j) { ev[j] = __expf(Q[i][d0 + j] - mx); sum += ev[j]; }
#pragma unroll
    for (int o = 1; o < 4; o <<= 1) sum += __shfl_xor(sum, o, 64);
    const float inv = 1.f / sum;
#pragma unroll
    for (int j = 0; j < 16; ++j) Q[i][d0 + j] = ev[j] * inv;
  }
  __syncthreads();
  {
    // At[i][d0+j] = sum_d Q[i][d] * klT[d][d0+j]   (b128 reads of Bb rows)
    float a[16];
#pragma unroll
    for (int j = 0; j < 16; ++j) a[j] = 0.f;
    for (int d = 0; d < 64; ++d) {
      const float qv = Q[i][d];
      const float4 b0 = *(const float4*)&Bb[d][d0];
      const float4 b1 = *(const float4*)&Bb[d][d0 + 4];
      const float4 b2 = *(const float4*)&Bb[d][d0 + 8];
      const float4 b3 = *(const float4*)&Bb[d][d0 + 12];
      a[0] += qv * b0.x;  a[1] += qv * b0.y;  a[2] += qv * b0.z;  a[3] += qv * b0.w;
      a[4] += qv * b1.x;  a[5] += qv * b1.y;  a[6] += qv * b1.z;  a[7] += qv * b1.w;
      a[8] += qv * b2.x;  a[9] += qv * b2.y;  a[10] += qv * b2.z; a[11] += qv * b2.w;
      a[12] += qv * b3.x; a[13] += qv * b3.y; a[14] += qv * b3.z; a[15] += qv * b3.w;
    }
#pragma unroll
    for (int j = 0; j < 16; ++j) At[i][d0 + j] = (d0 + j <= i) ? a[j] : 0.f;
  }
  __syncthreads();
  const size_t cb = ((size_t)(b * 8 + hk) * 16 + c) * 4096;
  for (int x = tid; x < 4096; x += 256) Bb[x >> 6][x & 63] = S_pre[cb + x];
  __syncthreads();
  float o[16];
#pragma unroll
  for (int j = 0; j < 16; ++j) o[j] = 0.f;
  for (int e = 0; e < 64; ++e) {
    const float qv = Q[i][e];
#pragma unroll
    for (int j = 0; j < 16; ++j) o[j] += qv * Bb[e][d0 + j];
  }
  __syncthreads();
  for (int x = tid; x < 4096; x += 256) Bb[x >> 6][x & 63] = upb[cb + x];
  __syncthreads();
  for (int j2 = 0; j2 < 64; ++j2) {
    const float av = At[i][j2];
#pragma unroll
    for (int j = 0; j < 16; ++j) o[j] += av * Bb[j2][d0 + j];
  }
  float* oc = o_comb + ((size_t)(b * Nc + c * 64 + i) * 32 + h) * 64 + d0;
#pragma unroll
  for (int j = 0; j < 16; ++j) oc[j] = 0.5f * o[j];
}

// ---------------------------------------------------------------------------
// Tile-copy helpers: 64x64 bf16 tile global -> LDS [row][LDK], 2 uint4/thread.
// ---------------------------------------------------------------------------
template <int LDK>
__device__ __forceinline__ void stage_tile(
    const bfu* __restrict__ g, size_t row_stride, bfu* dst, int tid)
{
  const int xr = tid >> 3;         // 0..31
  const int xc = (tid & 7) * 8;    // 0,8,..,56
#pragma unroll
  for (int hh = 0; hh < 2; ++hh) {
    const int row = xr + hh * 32;
    *(uint4*)&dst[(size_t)row * LDK + xc] =
        *(const uint4*)(g + (size_t)row * row_stride + xc);
  }
}

// ---------------------------------------------------------------------------
// Base attention pass A (MFMA): online m,l only.  Inputs pre-cast bf16.
// S^T orientation: A = K (m=j), B = Q (n=i), k = d.  1024 blocks x 256 thr.
// ---------------------------------------------------------------------------
__global__ __launch_bounds__(256) void ml_mfma_k(
    const bfu* __restrict__ qbf, const bfu* __restrict__ kbf,
    float* __restrict__ mbuf, float* __restrict__ lbuf)
{
  constexpr int LDK = 72;
  __shared__ __align__(16) bfu Qt[64 * LDK];  // [i][d]
  __shared__ __align__(16) bfu Kt[64 * LDK];  // [j][d]
  __shared__ float mred[4][64];
  __shared__ float lred[4][64];
  const int blk = blockIdx.x;
  const int ib = blk & 15, bh = blk >> 4;
  const int h = bh & 31, b = bh >> 5, hk = h >> 2;
  const int tid = threadIdx.x;
  const int wave = tid >> 6, lane = tid & 63;
  const int fm = lane & 15, quad = lane >> 4;
  const int wj = wave * 16;

  stage_tile<LDK>(qbf + ((size_t)(b * Nc + ib * 64) * 32 + h) * 64,
                  (size_t)32 * 64, Qt, tid);
  __syncthreads();
  frag_ab qb[4][2];
#pragma unroll
  for (int in = 0; in < 4; ++in)
#pragma unroll
    for (int kk = 0; kk < 2; ++kk)
      qb[in][kk] = *(const frag_ab*)&Qt[(size_t)(in * 16 + fm) * LDK + kk * 32 + quad * 8];

  float m[4], l[4];
#pragma unroll
  for (int in = 0; in < 4; ++in) { m[in] = -1e30f; l[in] = 0.f; }

  for (int jt = 0; jt <= ib; ++jt) {
    __syncthreads();
    stage_tile<LDK>(kbf + ((size_t)(b * Nc + jt * 64) * 8 + hk) * 64,
                    (size_t)8 * 64, Kt, tid);
    __syncthreads();
    frag_ab ka[2];
    ka[0] = *(const frag_ab*)&Kt[(size_t)(wj + fm) * LDK + quad * 8];
    ka[1] = *(const frag_ab*)&Kt[(size_t)(wj + fm) * LDK + 32 + quad * 8];
    const bool diag = (jt == ib);
#pragma unroll
    for (int in = 0; in < 4; ++in) {
      frag_cd acc = (frag_cd){0.f, 0.f, 0.f, 0.f};
      acc = __builtin_amdgcn_mfma_f32_16x16x32_bf16(ka[0], qb[in][0], acc, 0, 0, 0);
      acc = __builtin_amdgcn_mfma_f32_16x16x32_bf16(ka[1], qb[in][1], acc, 0, 0, 0);
      const int iloc = in * 16 + fm;
      float sv[4];
      bool vd[4];
      float tm = -1e30f;
#pragma unroll
      for (int r = 0; r < 4; ++r) {
        const int jloc = wj + quad * 4 + r;
        vd[r] = !diag || (jloc <= iloc);
        sv[r] = acc[r] * 0.125f;
        if (vd[r]) tm = fmaxf(tm, sv[r]);
      }
      const float mn = fmaxf(m[in], tm);
      float lsum = 0.f;
#pragma unroll
      for (int r = 0; r < 4; ++r)
        if (vd[r]) lsum += __expf(sv[r] - mn);
      l[in] = l[in] * __expf(m[in] - mn) + lsum;  // l==0 when m==-1e30, safe
      m[in] = mn;
    }
  }
#pragma unroll
  for (int in = 0; in < 4; ++in) {
    float mm = m[in], ll = l[in];
#pragma unroll
    for (int off = 16; off < 64; off <<= 1) {
      const float mo = __shfl_xor(mm, off, 64);
      const float lo = __shfl_xor(ll, off, 64);
      const float mn = fmaxf(mm, mo);
      ll = ll * __expf(mm - mn) + lo * __expf(mo - mn);
      mm = mn;
    }
    if (quad == 0) { mred[wave][in * 16 + fm] = mm; lred[wave][in * 16 + fm] = ll; }
  }
  __syncthreads();
  if (tid < 64) {
    float M = -1e30f;
#pragma unroll
    for (int w = 0; w < 4; ++w) M = fmaxf(M, mred[w][tid]);
    float L = 0.f;
#pragma unroll
    for (int w = 0; w < 4; ++w) L += lred[w][tid] * __expf(mred[w][tid] - M);
    const size_t rowi = (size_t)(b * 32 + h) * 1024 + ib * 64 + tid;
    mbuf[rowi] = M;
    lbuf[rowi] = L;
  }
}

// ---------------------------------------------------------------------------
// Base attention pass B (MFMA): recompute scores, p = exp(s-m)/l -> attn,
// PV via MFMA.  Inputs pre-cast bf16 (K) and pre-transposed bf16 (Vt).
// Writes oc_bf = bf16(o_comb + 0.5*o_base) directly.  1024 blocks x 256 thr.
// ---------------------------------------------------------------------------
__global__ __launch_bounds__(256) void pv_mfma_k(
    const bfu* __restrict__ qbf, const bfu* __restrict__ kbf,
    const bfu* __restrict__ vtbf, const float* __restrict__ mbuf,
    const float* __restrict__ lbuf, float* __restrict__ attn,
    const float* __restrict__ o_comb, bfu* __restrict__ oc_bf)
{
  constexpr int LDK = 72;
  __shared__ __align__(16) bfu Qt[64 * LDK];    // [i][d]
  __shared__ __align__(16) bfu Kt[64 * LDK];    // [j][d]
  __shared__ __align__(16) bfu Vt[64 * LDK];    // [dv][j]
  __shared__ __align__(16) bfu Pmat[64 * LDK];  // [i][j]
  const int blk = blockIdx.x;
  const int ib = blk & 15, bh = blk >> 4;
  const int h = bh & 31, b = bh >> 5, hk = h >> 2;
  const int tid = threadIdx.x;
  const int wave = tid >> 6, lane = tid & 63;
  const int fm = lane & 15, quad = lane >> 4;
  const int wj = wave * 16;   // score phase: wave's j slice
  const int im0 = wave * 16;  // PV phase: wave's i slice

  stage_tile<LDK>(qbf + ((size_t)(b * Nc + ib * 64) * 32 + h) * 64,
                  (size_t)32 * 64, Qt, tid);
  __syncthreads();
  frag_ab qb[4][2];
#pragma unroll
  for (int in = 0; in < 4; ++in)
#pragma unroll
    for (int kk = 0; kk < 2; ++kk)
      qb[in][kk] = *(const frag_ab*)&Qt[(size_t)(in * 16 + fm) * LDK + kk * 32 + quad * 8];

  float mi[4], il[4];
#pragma unroll
  for (int in = 0; in < 4; ++in) {
    const size_t rowi = (size_t)(b * 32 + h) * 1024 + ib * 64 + in * 16 + fm;
    mi[in] = mbuf[rowi];
    il[in] = 1.f / lbuf[rowi];
  }

  float* arow0 = attn + ((size_t)(b * 32 + h) * 1024 + ib * 64) * 1024;

  frag_cd o[4];
#pragma unroll
  for (int in = 0; in < 4; ++in) o[in] = (frag_cd){0.f, 0.f, 0.f, 0.f};

  for (int jt = 0; jt <= ib; ++jt) {
    __syncthreads();  // protect prev iter's Vt/Pmat reads
    stage_tile<LDK>(kbf + ((size_t)(b * Nc + jt * 64) * 8 + hk) * 64,
                    (size_t)8 * 64, Kt, tid);
    stage_tile<LDK>(vtbf + (size_t)(b * 8 + hk) * 64 * 1024 + jt * 64,
                    (size_t)1024, Vt, tid);
    __syncthreads();
    frag_ab ka[2];
    ka[0] = *(const frag_ab*)&Kt[(size_t)(wj + fm) * LDK + quad * 8];
    ka[1] = *(const frag_ab*)&Kt[(size_t)(wj + fm) * LDK + 32 + quad * 8];
    const bool diag = (jt == ib);
#pragma unroll
    for (int in = 0; in < 4; ++in) {
      frag_cd acc = (frag_cd){0.f, 0.f, 0.f, 0.f};
      acc = __builtin_amdgcn_mfma_f32_16x16x32_bf16(ka[0], qb[in][0], acc, 0, 0, 0);
      acc = __builtin_amdgcn_mfma_f32_16x16x32_bf16(ka[1], qb[in][1], acc, 0, 0, 0);
      const int iloc = in * 16 + fm;
      float p[4];
#pragma unroll
      for (int r = 0; r < 4; ++r) {
        const int jloc = wj + quad * 4 + r;
        const bool vdr = !diag || (jloc <= iloc);
        p[r] = vdr ? __expf(acc[r] * 0.125f - mi[in]) * il[in] : 0.f;
      }
      *(float4*)(arow0 + (size_t)iloc * 1024 + jt * 64 + wj + quad * 4) =
          make_float4(p[0], p[1], p[2], p[3]);
      ushort4 w;
      w.x = f2bf(p[0]); w.y = f2bf(p[1]); w.z = f2bf(p[2]); w.w = f2bf(p[3]);
      *(ushort4*)&Pmat[(size_t)iloc * LDK + wj + quad * 4] = w;
    }
    __syncthreads();
    frag_ab pa[2];
    pa[0] = *(const frag_ab*)&Pmat[(size_t)(im0 + fm) * LDK + quad * 8];
    pa[1] = *(const frag_ab*)&Pmat[(size_t)(im0 + fm) * LDK + 32 + quad * 8];
#pragma unroll
    for (int in = 0; in < 4; ++in) {
      frag_ab vb0 = *(const frag_ab*)&Vt[(size_t)(in * 16 + fm) * LDK + quad * 8];
      frag_ab vb1 = *(const frag_ab*)&Vt[(size_t)(in * 16 + fm) * LDK + 32 + quad * 8];
      o[in] = __builtin_amdgcn_mfma_f32_16x16x32_bf16(pa[0], vb0, o[in], 0, 0, 0);
      o[in] = __builtin_amdgcn_mfma_f32_16x16x32_bf16(pa[1], vb1, o[in], 0, 0, 0);
    }
  }
  // zero-fill non-causal tiles of attn
  for (int jt2 = ib + 1; jt2 < 16; ++jt2) {
    const float4 z = make_float4(0.f, 0.f, 0.f, 0.f);
    for (int x = tid; x < 1024; x += 256) {
      const int row = x >> 4, c4 = (x & 15) * 4;
      *(float4*)(arow0 + (size_t)row * 1024 + jt2 * 64 + c4) = z;
    }
  }
  // oc_bf = bf16(o_comb + 0.5*o)
#pragma unroll
  for (int in = 0; in < 4; ++in)
#pragma unroll
    for (int r = 0; r < 4; ++r) {
      const int i = im0 + quad * 4 + r;
      const size_t idx = ((size_t)(b * Nc + ib * 64 + i) * 32 + h) * 64 + in * 16 + fm;
      oc_bf[idx] = f2bf(o_comb[idx] + 0.5f * o[in][r]);
    }
}

// ---------------------------------------------------------------------------
extern "C" void kernel_launch(void* const* d_in, const int* in_sizes, int n_in,
                              void* d_out, int out_size, void* d_ws, size_t ws_size,
                              hipStream_t stream) {
  const float* hs = (const float*)d_in[0];
  const float* Wq = (const float*)d_in[1];
  const float* Wk = (const float*)d_in[2];
  const float* Wv = (const float*)d_in[3];
  const float* Wo = (const float*)d_in[4];
  float* out = (float*)d_out;                      // [B,N,HID]
  float* attn = out + (size_t)Bc * Nc * HIDc;      // [B,H,N,N]

  float* ws = (float*)d_ws;
  float* q_raw  = ws;                     // 4,194,304 f32
  float* k_raw  = q_raw + 4194304;        // 1,048,576
  float* v_raw  = k_raw + 1048576;        // 1,048,576
  float* kl     = v_raw + 1048576;        // 1,048,576
  float* gl     = kl + 1048576;           // 1,048,576
  float* u_ps   = gl + 1048576;           // 2,097,152
  float* w_ps   = u_ps + 2097152;         // 2,097,152
  float* upb    = w_ps + 2097152;         // 2,097,152
  float* S_pre  = upb + 2097152;          // 2,097,152
  float* o_comb = S_pre + 2097152;        // 4,194,304
  float* mbuf   = o_comb + 4194304;       // 65,536
  float* lbuf   = mbuf + 65536;           // 65,536
  bfu* bstart = (bfu*)(lbuf + 65536);
  bfu* hs_bf  = bstart;                   // 4,194,304 bf16
  bfu* WqT    = hs_bf + 4194304;          // 4,194,304
  bfu* WkT    = WqT + 4194304;            // 1,048,576
  bfu* WvT    = WkT + 1048576;            // 1,048,576
  bfu* WoT    = WvT + 1048576;            // 4,194,304
  bfu* oc_bf  = WoT + 4194304;            // 4,194,304
  // Aliases of regions dead after gemm_qkv_k (stream-ordered, safe):
  bfu* q_bf   = hs_bf;                    // 4,194,304 bf16 (aliases hs_bf)
  bfu* k_bf   = WqT;                      // 1,048,576 bf16 (aliases WqT)
  bfu* vt_bf  = WqT + 1048576;            // 1,048,576 bf16 (aliases WqT+1M)

  // Casts / weight transposes
  cast_bf16_k<<<4096, 256, 0, stream>>>(hs, hs_bf);
  transpose_cast_k<<<dim3(64, 64), 256, 0, stream>>>(Wq, WqT, 2048, 2048);
  transpose_cast_k<<<dim3(16, 64), 256, 0, stream>>>(Wk, WkT, 2048, 512);
  transpose_cast_k<<<dim3(16, 64), 256, 0, stream>>>(Wv, WvT, 2048, 512);
  transpose_cast_k<<<dim3(64, 64), 256, 0, stream>>>(Wo, WoT, 2048, 2048);
  // Fused Q/K/V projection (bf16 MFMA, global_load_lds staging, 384 blocks)
  gemm_qkv_k<<<dim3(24, 16), 256, 0, stream>>>(hs_bf, WqT, WkT, WvT,
                                               q_raw, k_raw, v_raw);
  // Pre-cast attention inputs (aliases dead after gemm_qkv_k)
  cast_bf16_k<<<4096, 256, 0, stream>>>(q_raw, q_bf);
  gates64_k<<<4096, 256, 0, stream>>>(k_raw, kl, gl, k_bf);
  transpose_v_k<<<256, 256, 0, stream>>>(v_raw, vt_bf);
  // Delta-rule
  chunk_prep_k<<<256, 256, 0, stream>>>(kl, v_raw, gl, u_ps, w_ps);
  scan_k<<<16, 512, 0, stream>>>(u_ps, w_ps, kl, upb, S_pre);
  // Linear-attention output (writes o_comb = 0.5*o_lin)
  olin_k<<<1024, 256, 0, stream>>>(q_raw, kl, upb, S_pre, o_comb);
  // Base causal attention: MFMA m,l pass then fused p/attn-write/PV pass
  ml_mfma_k<<<1024, 256, 0, stream>>>(q_bf, k_bf, mbuf, lbuf);
  pv_mfma_k<<<1024, 256, 0, stream>>>(q_bf, k_bf, vt_bf, mbuf, lbuf, attn,
                                      o_comb, oc_bf);
  // Output projection (reads bf16 written by pv_mfma_k)
  gemm_wo_k<<<dim3(16, 16), 256, 0, stream>>>(oc_bf, WoT, out);
}

// Round 6
// 676.677 us; speedup vs baseline: 1.1476x; 1.0861x over previous
//
#include <hip/hip_runtime.h>
#include <hip/hip_bf16.h>

// Problem constants
constexpr int Bc = 2, Nc = 1024, HIDc = 2048, Hc = 32, Dc = 64, HKVc = 8, NCc = 16;

typedef unsigned short bfu;  // raw bf16 bits
typedef __attribute__((ext_vector_type(8))) short frag_ab;  // 8 bf16 (4 VGPRs)
typedef __attribute__((ext_vector_type(4))) float frag_cd;  // 4 fp32 acc

__device__ __forceinline__ bfu f2bf(float f) {
  unsigned int u = __float_as_uint(f);
  unsigned int r = u + 0x7fffu + ((u >> 16) & 1u);  // RNE
  return (bfu)(r >> 16);
}
__device__ __forceinline__ ushort4 pack4(float4 v) {
  ushort4 r; r.x = f2bf(v.x); r.y = f2bf(v.y); r.z = f2bf(v.z); r.w = f2bf(v.w);
  return r;
}

// async global->LDS, 16B per lane (m97 pattern: lane-linear staging layout)
__device__ __forceinline__ void gl16(const bfu* g, bfu* l) {
  __builtin_amdgcn_global_load_lds(
      (const __attribute__((address_space(1))) void*)g,
      (__attribute__((address_space(3))) void*)l, 16, 0, 0);
}

// ---------------------------------------------------------------------------
// Flat cast fp32 -> bf16 (4 elements/thread)
// ---------------------------------------------------------------------------
__global__ __launch_bounds__(256) void cast_bf16_k(
    const float* __restrict__ in, bfu* __restrict__ out)
{
  const size_t i = ((size_t)blockIdx.x * 256 + threadIdx.x) * 4;
  *(ushort4*)(out + i) = pack4(*(const float4*)(in + i));
}

// ---------------------------------------------------------------------------
// Transpose + cast: W fp32 [K][N] -> WT bf16 [N][K].  32x32 tiles, 256 thr.
// ---------------------------------------------------------------------------
__global__ __launch_bounds__(256) void transpose_cast_k(
    const float* __restrict__ W, bfu* __restrict__ WT, int K, int N)
{
  __shared__ float t[32][33];
  const int bn = blockIdx.x * 32, bk = blockIdx.y * 32;
  const int x = threadIdx.x & 31, y = threadIdx.x >> 5;  // 32x8
#pragma unroll
  for (int i = 0; i < 32; i += 8)
    t[y + i][x] = W[(size_t)(bk + y + i) * N + bn + x];
  __syncthreads();
#pragma unroll
  for (int i = 0; i < 32; i += 8)
    WT[(size_t)(bn + y + i) * K + bk + x] = f2bf(t[x][y + i]);
}

// ---------------------------------------------------------------------------
// V transpose + cast: v fp32 [b,n,hk,dv] -> vt bf16 [b,hk,dv,n].  256 blocks.
// ---------------------------------------------------------------------------
__global__ __launch_bounds__(256) void transpose_v_k(
    const float* __restrict__ v, bfu* __restrict__ vt)
{
  __shared__ __align__(16) bfu T[64][72];
  const int blk = blockIdx.x;
  const int nt = blk & 15, bh = blk >> 4;  // n-tile, b*8+hk
  const int hk = bh & 7, b = bh >> 3;
  const int tid = threadIdx.x;
  const int n = tid >> 2, dv0 = (tid & 3) * 16;
  const float* src = v + ((size_t)(b * Nc + nt * 64 + n) * 8 + hk) * 64 + dv0;
#pragma unroll
  for (int e = 0; e < 16; ++e) T[dv0 + e][n] = f2bf(src[e]);
  __syncthreads();
  const int r = tid >> 3, c = (tid & 7) * 8;
#pragma unroll
  for (int hh = 0; hh < 2; ++hh) {
    const int dv = r + hh * 32;
    *(uint4*)(vt + ((size_t)(bh * 64 + dv)) * 1024 + nt * 64 + c) =
        *(const uint4*)&T[dv][c];
  }
}

// ---------------------------------------------------------------------------
// Shared MFMA GEMM body (m97 structure): A bf16 [M][2048] x BT bf16 [N][2048]
// -> C fp32 [M][Nn].  128x128 tile, BK=32, 256 thr (4 waves 2x2), linear LDS,
// global_load_lds dwordx4 staging.
// ---------------------------------------------------------------------------
__device__ __forceinline__ void gemm128_gl(
    const bfu* __restrict__ A, const bfu* __restrict__ BT,
    float* __restrict__ C, const int Nn, const int m0, const int n0,
    bfu* As, bfu* Bs)
{
  const int tid = threadIdx.x;
  const int wave = tid >> 6, lane = tid & 63;
  const int wm = (wave >> 1) * 64, wn = (wave & 1) * 64;
  const int fm = lane & 15, quad = lane >> 4;
  const int sr = tid >> 2, skc = (tid & 3) * 8;  // staging row / k-col

  frag_cd acc[4][4];
#pragma unroll
  for (int i = 0; i < 4; ++i)
#pragma unroll
    for (int j = 0; j < 4; ++j) acc[i][j] = (frag_cd){0.f, 0.f, 0.f, 0.f};

  const bfu* Ag = A + (size_t)(m0 + sr) * 2048 + skc;
  const bfu* Bg = BT + (size_t)(n0 + sr) * 2048 + skc;
  bfu* Al = As + tid * 8;   // lane-linear: tid*16 bytes
  bfu* Bl = Bs + tid * 8;

  for (int k0 = 0; k0 < 2048; k0 += 32) {
    gl16(Ag + k0, Al);
    gl16(Ag + k0 + (size_t)64 * 2048, Al + 64 * 32);
    gl16(Bg + k0, Bl);
    gl16(Bg + k0 + (size_t)64 * 2048, Bl + 64 * 32);
    __syncthreads();  // compiler drains vmcnt before s_barrier
    frag_ab a[4], b[4];
#pragma unroll
    for (int im = 0; im < 4; ++im)
      a[im] = *(const frag_ab*)&As[(size_t)(wm + im * 16 + fm) * 32 + quad * 8];
#pragma unroll
    for (int in = 0; in < 4; ++in)
      b[in] = *(const frag_ab*)&Bs[(size_t)(wn + in * 16 + fm) * 32 + quad * 8];
#pragma unroll
    for (int im = 0; im < 4; ++im)
#pragma unroll
      for (int in = 0; in < 4; ++in)
        acc[im][in] = __builtin_amdgcn_mfma_f32_16x16x32_bf16(
            a[im], b[in], acc[im][in], 0, 0, 0);
    __syncthreads();
  }
#pragma unroll
  for (int im = 0; im < 4; ++im)
#pragma unroll
    for (int in = 0; in < 4; ++in) {
      const int n = n0 + wn + in * 16 + fm;
#pragma unroll
      for (int r = 0; r < 4; ++r) {
        const int m = m0 + wm + im * 16 + quad * 4 + r;
        C[(size_t)m * Nn + n] = acc[im][in][r];
      }
    }
}

// Fused Q/K/V projection: all three GEMMs in one 384-block dispatch.
__global__ __launch_bounds__(256) void gemm_qkv_k(
    const bfu* __restrict__ A, const bfu* __restrict__ BTq,
    const bfu* __restrict__ BTk, const bfu* __restrict__ BTv,
    float* __restrict__ Cq, float* __restrict__ Ck, float* __restrict__ Cv)
{
  __shared__ __align__(16) bfu As[128 * 32];
  __shared__ __align__(16) bfu Bs[128 * 32];
  int bx = blockIdx.x;
  const bfu* BT; float* C; int Nn;
  if (bx < 16)      { BT = BTq; C = Cq; Nn = 2048; }
  else if (bx < 20) { BT = BTk; C = Ck; Nn = 512; bx -= 16; }
  else              { BT = BTv; C = Cv; Nn = 512; bx -= 20; }
  gemm128_gl(A, BT, C, Nn, blockIdx.y * 128, bx * 128, As, Bs);
}

// Output projection GEMM.
__global__ __launch_bounds__(256) void gemm_wo_k(
    const bfu* __restrict__ A, const bfu* __restrict__ BT, float* __restrict__ C)
{
  __shared__ __align__(16) bfu As[128 * 32];
  __shared__ __align__(16) bfu Bs[128 * 32];
  gemm128_gl(A, BT, C, 2048, blockIdx.y * 128, blockIdx.x * 128, As, Bs);
}

// ---------------------------------------------------------------------------
// Per-row (64-wide) softmax of k -> kl, log_sigmoid(k)/16 -> gl, and
// k_bf = bf16(k) (pre-cast for the attention kernels).
// ---------------------------------------------------------------------------
__global__ __launch_bounds__(256) void gates64_k(
    const float* __restrict__ kin, float* __restrict__ kl, float* __restrict__ gl,
    bfu* __restrict__ k_bf)
{
  const int r = blockIdx.x * 4 + (threadIdx.x >> 6);
  const int lane = threadIdx.x & 63;
  const size_t idx = (size_t)r * 64 + lane;
  const float x = kin[idx];
  k_bf[idx] = f2bf(x);
  float m = x;
#pragma unroll
  for (int o = 32; o > 0; o >>= 1) m = fmaxf(m, __shfl_xor(m, o, 64));
  const float e = __expf(x - m);
  float s = e;
#pragma unroll
  for (int o = 32; o > 0; o >>= 1) s += __shfl_xor(s, o, 64);
  kl[idx] = e / s;
  const float ls = fminf(x, 0.f) - log1pf(__expf(-fabsf(x)));
  gl[idx] = ls * 0.0625f;
}

// ---------------------------------------------------------------------------
// Per (b,hkv,chunk): triangular solves.  256 blocks.
// L-matmul reads klT (b128); solve is BLOCKED forward substitution:
// 16-row diagonal blocks (serial, 128 thr) + trailing updates (all 256 thr).
// Ascending-j accumulation order preserved -> bitwise identical results.
// ---------------------------------------------------------------------------
__global__ __launch_bounds__(256) void chunk_prep_k(
    const float* __restrict__ kl, const float* __restrict__ v,
    const float* __restrict__ gl, float* __restrict__ u_out, float* __restrict__ w_out)
{
  __shared__ __align__(16) float KC[64][68];  // klT, then L
  __shared__ float KB[64][65];
  __shared__ float VB[64][65];
  const int blk = blockIdx.x;
  const int c = blk & 15, bh = blk >> 4;
  const int hk = bh & 7, b = bh >> 3;
  const int tid = threadIdx.x;
  for (int x = tid; x < 4096; x += 256) {
    const int i = x >> 6, d = x & 63;
    const size_t src = ((size_t)(b * Nc + c * 64 + i) * 8 + hk) * 64 + d;
    const float kv = kl[src], g = gl[src], vv = v[src];
    KC[d][i] = kv; KB[i][d] = kv * g; VB[i][d] = vv * g;
  }
  __syncthreads();
  // L[i][j] = sum_d KB[i][d] * kl[j][d], strictly lower.  Thread: (i, 16 j's).
  const int li = tid >> 2, j0 = (tid & 3) * 16;
  float acc[16];
#pragma unroll
  for (int jj = 0; jj < 16; ++jj) acc[jj] = 0.f;
  for (int d = 0; d < 64; ++d) {
    const float kb = KB[li][d];
    const float4 c0v = *(const float4*)&KC[d][j0];
    const float4 c1v = *(const float4*)&KC[d][j0 + 4];
    const float4 c2v = *(const float4*)&KC[d][j0 + 8];
    const float4 c3v = *(const float4*)&KC[d][j0 + 12];
    acc[0] += kb * c0v.x;  acc[1] += kb * c0v.y;  acc[2] += kb * c0v.z;  acc[3] += kb * c0v.w;
    acc[4] += kb * c1v.x;  acc[5] += kb * c1v.y;  acc[6] += kb * c1v.z;  acc[7] += kb * c1v.w;
    acc[8] += kb * c2v.x;  acc[9] += kb * c2v.y;  acc[10] += kb * c2v.z; acc[11] += kb * c2v.w;
    acc[12] += kb * c3v.x; acc[13] += kb * c3v.y; acc[14] += kb * c3v.z; acc[15] += kb * c3v.w;
  }
  __syncthreads();
#pragma unroll
  for (int jj = 0; jj < 16; ++jj)
    KC[li][j0 + jj] = (j0 + jj < li) ? acc[jj] : 0.f;
  __syncthreads();
  // Blocked forward substitution on X = [VB | KB] (unit lower L in KC).
  for (int r0 = 0; r0 < 64; r0 += 16) {
    if (r0 > 0) {
      // trailing update: X[r0+ii][d] -= sum_{j<r0} L[r0+ii][j] * X[j][d]
      for (int p = tid; p < 2048; p += 256) {
        const int ii = p >> 7, dc = p & 127;
        float (*X)[65] = (dc < 64) ? VB : KB;
        const int d = dc & 63;
        float a2 = X[r0 + ii][d];
        for (int j = 0; j < r0; ++j) a2 -= KC[r0 + ii][j] * X[j][d];
        X[r0 + ii][d] = a2;
      }
      __syncthreads();
    }
    // diagonal 16x16 solve (serial over rows, parallel over 128 cols)
    if (tid < 128) {
      const int d = tid & 63;
      float (*X)[65] = (tid < 64) ? VB : KB;
      for (int i = r0 + 1; i < r0 + 16; ++i) {
        float a2 = X[i][d];
        for (int j = r0; j < i; ++j) a2 -= KC[i][j] * X[j][d];
        X[i][d] = a2;
      }
    }
    __syncthreads();
  }
  for (int x = tid; x < 4096; x += 256) {
    u_out[(size_t)blk * 4096 + x] = VB[x >> 6][x & 63];
    w_out[(size_t)blk * 4096 + x] = KB[x >> 6][x & 63];
  }
}

// ---------------------------------------------------------------------------
// Serial scan over chunks per (b,hkv), COLUMN-SPLIT 4-ways: the d_v columns
// of S are independent through the recurrence, so 64 blocks (16 bh x 4 col-
// groups of 16) each run the full 16-chunk scan on their 16-column slice.
// w/k tiles staged redundantly per group (L2-cached).  256 threads.
// Per-output accumulation order identical to the unsplit version.
// ---------------------------------------------------------------------------
__global__ __launch_bounds__(256) void scan_k(
    const float* __restrict__ u_ps, const float* __restrict__ w_ps,
    const float* __restrict__ kl, float* __restrict__ u_p, float* __restrict__ S_pre)
{
  __shared__ __align__(16) float S[64][20];   // [e][c-slice]
  __shared__ __align__(16) float up[64][20];  // [i][c-slice]
  __shared__ __align__(16) float kw[64][68];  // w tile (full)
  __shared__ __align__(16) float kt[64][68];  // kl tile (full)
  const int blk = blockIdx.x;   // 64 blocks
  const int cg = blk & 3;       // column group (16 cols)
  const int bh = blk >> 2;
  const int hk = bh & 7, b = bh >> 3;
  const int t = threadIdx.x;    // 256
  const int row = t >> 2;       // 0..63
  const int c0 = (t & 3) * 4;   // 0,4,8,12 within slice
  const int cbase = cg * 16;    // global column offset
  for (int x = t; x < 1024; x += 256) S[x >> 4][x & 15] = 0.f;
  __syncthreads();
  for (int c = 0; c < 16; ++c) {
    const size_t cb = ((size_t)bh * 16 + c) * 4096;
    // prefetch this chunk's u_ps slice (no dependence on S)
    const float4 upre = *(const float4*)(u_ps + cb + row * 64 + cbase + c0);
    // stage full w and kl tiles (vectorized)
    for (int x = t; x < 1024; x += 256) {
      const int i = x >> 4, d4 = (x & 15) * 4;
      *(float4*)&kw[i][d4] = *(const float4*)(w_ps + cb + i * 64 + d4);
      *(float4*)&kt[i][d4] =
          *(const float4*)(kl + ((size_t)(b * Nc + c * 64 + i) * 8 + hk) * 64 + d4);
    }
    // spill this block's S slice to S_pre
    for (int x = t; x < 1024; x += 256) {
      const int i = x >> 4, cc = x & 15;
      S_pre[cb + i * 64 + cbase + cc] = S[i][cc];
    }
    __syncthreads();
    // phase 1: up[row][c] = u_ps - sum_e w[row][e] * S[e][c]
    {
      float a0 = upre.x, a1 = upre.y, a2 = upre.z, a3 = upre.w;
      for (int e4 = 0; e4 < 64; e4 += 4) {
        const float4 wv4 = *(const float4*)&kw[row][e4];
#pragma unroll
        for (int ee = 0; ee < 4; ++ee) {
          const float wv = ((const float*)&wv4)[ee];
          const float4 sv = *(const float4*)&S[e4 + ee][c0];
          a0 -= wv * sv.x; a1 -= wv * sv.y; a2 -= wv * sv.z; a3 -= wv * sv.w;
        }
      }
      const float4 o = make_float4(a0, a1, a2, a3);
      *(float4*)&up[row][c0] = o;
      *(float4*)(u_p + cb + row * 64 + cbase + c0) = o;
    }
    __syncthreads();
    // phase 2: S[row][c] += sum_i kt[i][row] * up[i][c]
    {
      const float4 sv = *(const float4*)&S[row][c0];
      float s0 = sv.x, s1 = sv.y, s2 = sv.z, s3 = sv.w;
      for (int i = 0; i < 64; ++i) {
        const float kv = kt[i][row];
        const float4 uv = *(const float4*)&up[i][c0];
        s0 += kv * uv.x; s1 += kv * uv.y; s2 += kv * uv.z; s3 += kv * uv.w;
      }
      *(float4*)&S[row][c0] = make_float4(s0, s1, s2, s3);
    }
    __syncthreads();
  }
}

// ---------------------------------------------------------------------------
// o_lin per (b,h,chunk).  1024 blocks.
// ---------------------------------------------------------------------------
__global__ __launch_bounds__(256) void olin_k(
    const float* __restrict__ qraw, const float* __restrict__ kl,
    const float* __restrict__ upb, const float* __restrict__ S_pre,
    float* __restrict__ o_comb)
{
  __shared__ float Q[64][65];
  __shared__ __align__(16) float Bb[64][68];
  __shared__ float At[64][65];
  const int blk = blockIdx.x;
  const int c = blk & 15, bh = blk >> 4;
  const int h = bh & 31, b = bh >> 5, hk = h >> 2;
  const int tid = threadIdx.x;
  const int i = tid >> 2, d0 = (tid & 3) * 16;
  for (int x = tid; x < 4096; x += 256) {
    const int r = x >> 6, d = x & 63;
    Q[r][d] = qraw[((size_t)(b * Nc + c * 64 + r) * 32 + h) * 64 + d];
    Bb[d][r] = kl[((size_t)(b * Nc + c * 64 + r) * 8 + hk) * 64 + d];  // klT
  }
  __syncthreads();
  {
    float mx = -1e30f;
#pragma unroll
    for (int j = 0; j < 16; ++j) mx = fmaxf(mx, Q[i][d0 + j]);
#pragma unroll
    for (int o = 1; o < 4; o <<= 1) mx = fmaxf(mx, __shfl_xor(mx, o, 64));
    float ev[16];
    float sum = 0.f;
#pragma unroll
    for (int j = 0; j < 16; ++j) { ev[j] = __expf(Q[i][d0 + j] - mx); sum += ev[j]; }
#pragma unroll
    for (int o = 1; o < 4; o <<= 1) sum += __shfl_xor(sum, o, 64);
    const float inv = 1.f / sum;
#pragma unroll
    for (int j = 0; j < 16; ++j) Q[i][d0 + j] = ev[j] * inv;
  }
  __syncthreads();
  {
    // At[i][d0+j] = sum_d Q[i][d] * klT[d][d0+j]   (b128 reads of Bb rows)
    float a[16];
#pragma unroll
    for (int j = 0; j < 16; ++j) a[j] = 0.f;
    for (int d = 0; d < 64; ++d) {
      const float qv = Q[i][d];
      const float4 b0 = *(const float4*)&Bb[d][d0];
      const float4 b1 = *(const float4*)&Bb[d][d0 + 4];
      const float4 b2 = *(const float4*)&Bb[d][d0 + 8];
      const float4 b3 = *(const float4*)&Bb[d][d0 + 12];
      a[0] += qv * b0.x;  a[1] += qv * b0.y;  a[2] += qv * b0.z;  a[3] += qv * b0.w;
      a[4] += qv * b1.x;  a[5] += qv * b1.y;  a[6] += qv * b1.z;  a[7] += qv * b1.w;
      a[8] += qv * b2.x;  a[9] += qv * b2.y;  a[10] += qv * b2.z; a[11] += qv * b2.w;
      a[12] += qv * b3.x; a[13] += qv * b3.y; a[14] += qv * b3.z; a[15] += qv * b3.w;
    }
#pragma unroll
    for (int j = 0; j < 16; ++j) At[i][d0 + j] = (d0 + j <= i) ? a[j] : 0.f;
  }
  __syncthreads();
  const size_t cb = ((size_t)(b * 8 + hk) * 16 + c) * 4096;
  for (int x = tid; x < 4096; x += 256) Bb[x >> 6][x & 63] = S_pre[cb + x];
  __syncthreads();
  float o[16];
#pragma unroll
  for (int j = 0; j < 16; ++j) o[j] = 0.f;
  for (int e = 0; e < 64; ++e) {
    const float qv = Q[i][e];
#pragma unroll
    for (int j = 0; j < 16; ++j) o[j] += qv * Bb[e][d0 + j];
  }
  __syncthreads();
  for (int x = tid; x < 4096; x += 256) Bb[x >> 6][x & 63] = upb[cb + x];
  __syncthreads();
  for (int j2 = 0; j2 < 64; ++j2) {
    const float av = At[i][j2];
#pragma unroll
    for (int j = 0; j < 16; ++j) o[j] += av * Bb[j2][d0 + j];
  }
  float* oc = o_comb + ((size_t)(b * Nc + c * 64 + i) * 32 + h) * 64 + d0;
#pragma unroll
  for (int j = 0; j < 16; ++j) oc[j] = 0.5f * o[j];
}

// ---------------------------------------------------------------------------
// Tile-copy helpers: 64x64 bf16 tile global -> LDS [row][LDK], 2 uint4/thread.
// ---------------------------------------------------------------------------
template <int LDK>
__device__ __forceinline__ void stage_tile(
    const bfu* __restrict__ g, size_t row_stride, bfu* dst, int tid)
{
  const int xr = tid >> 3;         // 0..31
  const int xc = (tid & 7) * 8;    // 0,8,..,56
#pragma unroll
  for (int hh = 0; hh < 2; ++hh) {
    const int row = xr + hh * 32;
    *(uint4*)&dst[(size_t)row * LDK + xc] =
        *(const uint4*)(g + (size_t)row * row_stride + xc);
  }
}

// ---------------------------------------------------------------------------
// Base attention pass A (MFMA): online m,l only.  Inputs pre-cast bf16.
// S^T orientation: A = K (m=j), B = Q (n=i), k = d.  1024 blocks x 256 thr.
// ---------------------------------------------------------------------------
__global__ __launch_bounds__(256) void ml_mfma_k(
    const bfu* __restrict__ qbf, const bfu* __restrict__ kbf,
    float* __restrict__ mbuf, float* __restrict__ lbuf)
{
  constexpr int LDK = 72;
  __shared__ __align__(16) bfu Qt[64 * LDK];  // [i][d]
  __shared__ __align__(16) bfu Kt[64 * LDK];  // [j][d]
  __shared__ float mred[4][64];
  __shared__ float lred[4][64];
  const int blk = blockIdx.x;
  const int ib = blk & 15, bh = blk >> 4;
  const int h = bh & 31, b = bh >> 5, hk = h >> 2;
  const int tid = threadIdx.x;
  const int wave = tid >> 6, lane = tid & 63;
  const int fm = lane & 15, quad = lane >> 4;
  const int wj = wave * 16;

  stage_tile<LDK>(qbf + ((size_t)(b * Nc + ib * 64) * 32 + h) * 64,
                  (size_t)32 * 64, Qt, tid);
  __syncthreads();
  frag_ab qb[4][2];
#pragma unroll
  for (int in = 0; in < 4; ++in)
#pragma unroll
    for (int kk = 0; kk < 2; ++kk)
      qb[in][kk] = *(const frag_ab*)&Qt[(size_t)(in * 16 + fm) * LDK + kk * 32 + quad * 8];

  float m[4], l[4];
#pragma unroll
  for (int in = 0; in < 4; ++in) { m[in] = -1e30f; l[in] = 0.f; }

  for (int jt = 0; jt <= ib; ++jt) {
    __syncthreads();
    stage_tile<LDK>(kbf + ((size_t)(b * Nc + jt * 64) * 8 + hk) * 64,
                    (size_t)8 * 64, Kt, tid);
    __syncthreads();
    frag_ab ka[2];
    ka[0] = *(const frag_ab*)&Kt[(size_t)(wj + fm) * LDK + quad * 8];
    ka[1] = *(const frag_ab*)&Kt[(size_t)(wj + fm) * LDK + 32 + quad * 8];
    const bool diag = (jt == ib);
#pragma unroll
    for (int in = 0; in < 4; ++in) {
      frag_cd acc = (frag_cd){0.f, 0.f, 0.f, 0.f};
      acc = __builtin_amdgcn_mfma_f32_16x16x32_bf16(ka[0], qb[in][0], acc, 0, 0, 0);
      acc = __builtin_amdgcn_mfma_f32_16x16x32_bf16(ka[1], qb[in][1], acc, 0, 0, 0);
      const int iloc = in * 16 + fm;
      float sv[4];
      bool vd[4];
      float tm = -1e30f;
#pragma unroll
      for (int r = 0; r < 4; ++r) {
        const int jloc = wj + quad * 4 + r;
        vd[r] = !diag || (jloc <= iloc);
        sv[r] = acc[r] * 0.125f;
        if (vd[r]) tm = fmaxf(tm, sv[r]);
      }
      const float mn = fmaxf(m[in], tm);
      float lsum = 0.f;
#pragma unroll
      for (int r = 0; r < 4; ++r)
        if (vd[r]) lsum += __expf(sv[r] - mn);
      l[in] = l[in] * __expf(m[in] - mn) + lsum;  // l==0 when m==-1e30, safe
      m[in] = mn;
    }
  }
#pragma unroll
  for (int in = 0; in < 4; ++in) {
    float mm = m[in], ll = l[in];
#pragma unroll
    for (int off = 16; off < 64; off <<= 1) {
      const float mo = __shfl_xor(mm, off, 64);
      const float lo = __shfl_xor(ll, off, 64);
      const float mn = fmaxf(mm, mo);
      ll = ll * __expf(mm - mn) + lo * __expf(mo - mn);
      mm = mn;
    }
    if (quad == 0) { mred[wave][in * 16 + fm] = mm; lred[wave][in * 16 + fm] = ll; }
  }
  __syncthreads();
  if (tid < 64) {
    float M = -1e30f;
#pragma unroll
    for (int w = 0; w < 4; ++w) M = fmaxf(M, mred[w][tid]);
    float L = 0.f;
#pragma unroll
    for (int w = 0; w < 4; ++w) L += lred[w][tid] * __expf(mred[w][tid] - M);
    const size_t rowi = (size_t)(b * 32 + h) * 1024 + ib * 64 + tid;
    mbuf[rowi] = M;
    lbuf[rowi] = L;
  }
}

// ---------------------------------------------------------------------------
// Base attention pass B (MFMA): recompute scores, p = exp(s-m)/l -> attn,
// PV via MFMA.  Inputs pre-cast bf16 (K) and pre-transposed bf16 (Vt).
// Writes oc_bf = bf16(o_comb + 0.5*o_base) directly.  1024 blocks x 256 thr.
// ---------------------------------------------------------------------------
__global__ __launch_bounds__(256) void pv_mfma_k(
    const bfu* __restrict__ qbf, const bfu* __restrict__ kbf,
    const bfu* __restrict__ vtbf, const float* __restrict__ mbuf,
    const float* __restrict__ lbuf, float* __restrict__ attn,
    const float* __restrict__ o_comb, bfu* __restrict__ oc_bf)
{
  constexpr int LDK = 72;
  __shared__ __align__(16) bfu Qt[64 * LDK];    // [i][d]
  __shared__ __align__(16) bfu Kt[64 * LDK];    // [j][d]
  __shared__ __align__(16) bfu Vt[64 * LDK];    // [dv][j]
  __shared__ __align__(16) bfu Pmat[64 * LDK];  // [i][j]
  const int blk = blockIdx.x;
  const int ib = blk & 15, bh = blk >> 4;
  const int h = bh & 31, b = bh >> 5, hk = h >> 2;
  const int tid = threadIdx.x;
  const int wave = tid >> 6, lane = tid & 63;
  const int fm = lane & 15, quad = lane >> 4;
  const int wj = wave * 16;   // score phase: wave's j slice
  const int im0 = wave * 16;  // PV phase: wave's i slice

  stage_tile<LDK>(qbf + ((size_t)(b * Nc + ib * 64) * 32 + h) * 64,
                  (size_t)32 * 64, Qt, tid);
  __syncthreads();
  frag_ab qb[4][2];
#pragma unroll
  for (int in = 0; in < 4; ++in)
#pragma unroll
    for (int kk = 0; kk < 2; ++kk)
      qb[in][kk] = *(const frag_ab*)&Qt[(size_t)(in * 16 + fm) * LDK + kk * 32 + quad * 8];

  float mi[4], il[4];
#pragma unroll
  for (int in = 0; in < 4; ++in) {
    const size_t rowi = (size_t)(b * 32 + h) * 1024 + ib * 64 + in * 16 + fm;
    mi[in] = mbuf[rowi];
    il[in] = 1.f / lbuf[rowi];
  }

  float* arow0 = attn + ((size_t)(b * 32 + h) * 1024 + ib * 64) * 1024;

  frag_cd o[4];
#pragma unroll
  for (int in = 0; in < 4; ++in) o[in] = (frag_cd){0.f, 0.f, 0.f, 0.f};

  for (int jt = 0; jt <= ib; ++jt) {
    __syncthreads();  // protect prev iter's Vt/Pmat reads
    stage_tile<LDK>(kbf + ((size_t)(b * Nc + jt * 64) * 8 + hk) * 64,
                    (size_t)8 * 64, Kt, tid);
    stage_tile<LDK>(vtbf + (size_t)(b * 8 + hk) * 64 * 1024 + jt * 64,
                    (size_t)1024, Vt, tid);
    __syncthreads();
    frag_ab ka[2];
    ka[0] = *(const frag_ab*)&Kt[(size_t)(wj + fm) * LDK + quad * 8];
    ka[1] = *(const frag_ab*)&Kt[(size_t)(wj + fm) * LDK + 32 + quad * 8];
    const bool diag = (jt == ib);
#pragma unroll
    for (int in = 0; in < 4; ++in) {
      frag_cd acc = (frag_cd){0.f, 0.f, 0.f, 0.f};
      acc = __builtin_amdgcn_mfma_f32_16x16x32_bf16(ka[0], qb[in][0], acc, 0, 0, 0);
      acc = __builtin_amdgcn_mfma_f32_16x16x32_bf16(ka[1], qb[in][1], acc, 0, 0, 0);
      const int iloc = in * 16 + fm;
      float p[4];
#pragma unroll
      for (int r = 0; r < 4; ++r) {
        const int jloc = wj + quad * 4 + r;
        const bool vdr = !diag || (jloc <= iloc);
        p[r] = vdr ? __expf(acc[r] * 0.125f - mi[in]) * il[in] : 0.f;
      }
      *(float4*)(arow0 + (size_t)iloc * 1024 + jt * 64 + wj + quad * 4) =
          make_float4(p[0], p[1], p[2], p[3]);
      ushort4 w;
      w.x = f2bf(p[0]); w.y = f2bf(p[1]); w.z = f2bf(p[2]); w.w = f2bf(p[3]);
      *(ushort4*)&Pmat[(size_t)iloc * LDK + wj + quad * 4] = w;
    }
    __syncthreads();
    frag_ab pa[2];
    pa[0] = *(const frag_ab*)&Pmat[(size_t)(im0 + fm) * LDK + quad * 8];
    pa[1] = *(const frag_ab*)&Pmat[(size_t)(im0 + fm) * LDK + 32 + quad * 8];
#pragma unroll
    for (int in = 0; in < 4; ++in) {
      frag_ab vb0 = *(const frag_ab*)&Vt[(size_t)(in * 16 + fm) * LDK + quad * 8];
      frag_ab vb1 = *(const frag_ab*)&Vt[(size_t)(in * 16 + fm) * LDK + 32 + quad * 8];
      o[in] = __builtin_amdgcn_mfma_f32_16x16x32_bf16(pa[0], vb0, o[in], 0, 0, 0);
      o[in] = __builtin_amdgcn_mfma_f32_16x16x32_bf16(pa[1], vb1, o[in], 0, 0, 0);
    }
  }
  // zero-fill non-causal tiles of attn
  for (int jt2 = ib + 1; jt2 < 16; ++jt2) {
    const float4 z = make_float4(0.f, 0.f, 0.f, 0.f);
    for (int x = tid; x < 1024; x += 256) {
      const int row = x >> 4, c4 = (x & 15) * 4;
      *(float4*)(arow0 + (size_t)row * 1024 + jt2 * 64 + c4) = z;
    }
  }
  // oc_bf = bf16(o_comb + 0.5*o)
#pragma unroll
  for (int in = 0; in < 4; ++in)
#pragma unroll
    for (int r = 0; r < 4; ++r) {
      const int i = im0 + quad * 4 + r;
      const size_t idx = ((size_t)(b * Nc + ib * 64 + i) * 32 + h) * 64 + in * 16 + fm;
      oc_bf[idx] = f2bf(o_comb[idx] + 0.5f * o[in][r]);
    }
}

// ---------------------------------------------------------------------------
extern "C" void kernel_launch(void* const* d_in, const int* in_sizes, int n_in,
                              void* d_out, int out_size, void* d_ws, size_t ws_size,
                              hipStream_t stream) {
  const float* hs = (const float*)d_in[0];
  const float* Wq = (const float*)d_in[1];
  const float* Wk = (const float*)d_in[2];
  const float* Wv = (const float*)d_in[3];
  const float* Wo = (const float*)d_in[4];
  float* out = (float*)d_out;                      // [B,N,HID]
  float* attn = out + (size_t)Bc * Nc * HIDc;      // [B,H,N,N]

  float* ws = (float*)d_ws;
  float* q_raw  = ws;                     // 4,194,304 f32
  float* k_raw  = q_raw + 4194304;        // 1,048,576
  float* v_raw  = k_raw + 1048576;        // 1,048,576
  float* kl     = v_raw + 1048576;        // 1,048,576
  float* gl     = kl + 1048576;           // 1,048,576
  float* u_ps   = gl + 1048576;           // 2,097,152
  float* w_ps   = u_ps + 2097152;         // 2,097,152
  float* upb    = w_ps + 2097152;         // 2,097,152
  float* S_pre  = upb + 2097152;          // 2,097,152
  float* o_comb = S_pre + 2097152;        // 4,194,304
  float* mbuf   = o_comb + 4194304;       // 65,536
  float* lbuf   = mbuf + 65536;           // 65,536
  bfu* bstart = (bfu*)(lbuf + 65536);
  bfu* hs_bf  = bstart;                   // 4,194,304 bf16
  bfu* WqT    = hs_bf + 4194304;          // 4,194,304
  bfu* WkT    = WqT + 4194304;            // 1,048,576
  bfu* WvT    = WkT + 1048576;            // 1,048,576
  bfu* WoT    = WvT + 1048576;            // 4,194,304
  bfu* oc_bf  = WoT + 4194304;            // 4,194,304
  // Aliases of regions dead after gemm_qkv_k (stream-ordered, safe):
  bfu* q_bf   = hs_bf;                    // 4,194,304 bf16 (aliases hs_bf)
  bfu* k_bf   = WqT;                      // 1,048,576 bf16 (aliases WqT)
  bfu* vt_bf  = WqT + 1048576;            // 1,048,576 bf16 (aliases WqT+1M)

  // Casts / weight transposes
  cast_bf16_k<<<4096, 256, 0, stream>>>(hs, hs_bf);
  transpose_cast_k<<<dim3(64, 64), 256, 0, stream>>>(Wq, WqT, 2048, 2048);
  transpose_cast_k<<<dim3(16, 64), 256, 0, stream>>>(Wk, WkT, 2048, 512);
  transpose_cast_k<<<dim3(16, 64), 256, 0, stream>>>(Wv, WvT, 2048, 512);
  transpose_cast_k<<<dim3(64, 64), 256, 0, stream>>>(Wo, WoT, 2048, 2048);
  // Fused Q/K/V projection (bf16 MFMA, global_load_lds staging, 384 blocks)
  gemm_qkv_k<<<dim3(24, 16), 256, 0, stream>>>(hs_bf, WqT, WkT, WvT,
                                               q_raw, k_raw, v_raw);
  // Pre-cast attention inputs (aliases dead after gemm_qkv_k)
  cast_bf16_k<<<4096, 256, 0, stream>>>(q_raw, q_bf);
  gates64_k<<<4096, 256, 0, stream>>>(k_raw, kl, gl, k_bf);
  transpose_v_k<<<256, 256, 0, stream>>>(v_raw, vt_bf);
  // Delta-rule
  chunk_prep_k<<<256, 256, 0, stream>>>(kl, v_raw, gl, u_ps, w_ps);
  scan_k<<<64, 256, 0, stream>>>(u_ps, w_ps, kl, upb, S_pre);
  // Linear-attention output (writes o_comb = 0.5*o_lin)
  olin_k<<<1024, 256, 0, stream>>>(q_raw, kl, upb, S_pre, o_comb);
  // Base causal attention: MFMA m,l pass then fused p/attn-write/PV pass
  ml_mfma_k<<<1024, 256, 0, stream>>>(q_bf, k_bf, mbuf, lbuf);
  pv_mfma_k<<<1024, 256, 0, stream>>>(q_bf, k_bf, vt_bf, mbuf, lbuf, attn,
                                      o_comb, oc_bf);
  // Output projection (reads bf16 written by pv_mfma_k)
  gemm_wo_k<<<dim3(16, 16), 256, 0, stream>>>(oc_bf, WoT, out);
}

// Round 7
// 650.945 us; speedup vs baseline: 1.1929x; 1.0395x over previous
//
#include <hip/hip_runtime.h>
#include <hip/hip_bf16.h>

// Problem constants
constexpr int Bc = 2, Nc = 1024, HIDc = 2048, Hc = 32, Dc = 64, HKVc = 8, NCc = 16;

typedef unsigned short bfu;  // raw bf16 bits
typedef __attribute__((ext_vector_type(8))) short frag_ab;  // 8 bf16 (4 VGPRs)
typedef __attribute__((ext_vector_type(4))) float frag_cd;  // 4 fp32 acc

__device__ __forceinline__ bfu f2bf(float f) {
  unsigned int u = __float_as_uint(f);
  unsigned int r = u + 0x7fffu + ((u >> 16) & 1u);  // RNE
  return (bfu)(r >> 16);
}
__device__ __forceinline__ ushort4 pack4(float4 v) {
  ushort4 r; r.x = f2bf(v.x); r.y = f2bf(v.y); r.z = f2bf(v.z); r.w = f2bf(v.w);
  return r;
}

// async global->LDS, 16B per lane (m97 pattern: lane-linear staging layout)
__device__ __forceinline__ void gl16(const bfu* g, bfu* l) {
  __builtin_amdgcn_global_load_lds(
      (const __attribute__((address_space(1))) void*)g,
      (__attribute__((address_space(3))) void*)l, 16, 0, 0);
}

// ---------------------------------------------------------------------------
// Flat cast fp32 -> bf16 (4 elements/thread)
// ---------------------------------------------------------------------------
__global__ __launch_bounds__(256) void cast_bf16_k(
    const float* __restrict__ in, bfu* __restrict__ out)
{
  const size_t i = ((size_t)blockIdx.x * 256 + threadIdx.x) * 4;
  *(ushort4*)(out + i) = pack4(*(const float4*)(in + i));
}

// ---------------------------------------------------------------------------
// Transpose + cast: W fp32 [K][N] -> WT bf16 [N][K].  32x32 tiles, 256 thr.
// ---------------------------------------------------------------------------
__global__ __launch_bounds__(256) void transpose_cast_k(
    const float* __restrict__ W, bfu* __restrict__ WT, int K, int N)
{
  __shared__ float t[32][33];
  const int bn = blockIdx.x * 32, bk = blockIdx.y * 32;
  const int x = threadIdx.x & 31, y = threadIdx.x >> 5;  // 32x8
#pragma unroll
  for (int i = 0; i < 32; i += 8)
    t[y + i][x] = W[(size_t)(bk + y + i) * N + bn + x];
  __syncthreads();
#pragma unroll
  for (int i = 0; i < 32; i += 8)
    WT[(size_t)(bn + y + i) * K + bk + x] = f2bf(t[x][y + i]);
}

// ---------------------------------------------------------------------------
// V transpose + cast: v fp32 [b,n,hk,dv] -> vt bf16 [b,hk,dv,n].  256 blocks.
// ---------------------------------------------------------------------------
__global__ __launch_bounds__(256) void transpose_v_k(
    const float* __restrict__ v, bfu* __restrict__ vt)
{
  __shared__ __align__(16) bfu T[64][72];
  const int blk = blockIdx.x;
  const int nt = blk & 15, bh = blk >> 4;  // n-tile, b*8+hk
  const int hk = bh & 7, b = bh >> 3;
  const int tid = threadIdx.x;
  const int n = tid >> 2, dv0 = (tid & 3) * 16;
  const float* src = v + ((size_t)(b * Nc + nt * 64 + n) * 8 + hk) * 64 + dv0;
#pragma unroll
  for (int e = 0; e < 16; ++e) T[dv0 + e][n] = f2bf(src[e]);
  __syncthreads();
  const int r = tid >> 3, c = (tid & 7) * 8;
#pragma unroll
  for (int hh = 0; hh < 2; ++hh) {
    const int dv = r + hh * 32;
    *(uint4*)(vt + ((size_t)(bh * 64 + dv)) * 1024 + nt * 64 + c) =
        *(const uint4*)&T[dv][c];
  }
}

// ---------------------------------------------------------------------------
// Shared MFMA GEMM body (m97 structure): A bf16 [M][2048] x BT bf16 [N][2048]
// -> C fp32 [M][Nn].  128x128 tile, BK=32, 256 thr (4 waves 2x2), linear LDS,
// global_load_lds dwordx4 staging.
// ---------------------------------------------------------------------------
__device__ __forceinline__ void gemm128_gl(
    const bfu* __restrict__ A, const bfu* __restrict__ BT,
    float* __restrict__ C, const int Nn, const int m0, const int n0,
    bfu* As, bfu* Bs)
{
  const int tid = threadIdx.x;
  const int wave = tid >> 6, lane = tid & 63;
  const int wm = (wave >> 1) * 64, wn = (wave & 1) * 64;
  const int fm = lane & 15, quad = lane >> 4;
  const int sr = tid >> 2, skc = (tid & 3) * 8;  // staging row / k-col

  frag_cd acc[4][4];
#pragma unroll
  for (int i = 0; i < 4; ++i)
#pragma unroll
    for (int j = 0; j < 4; ++j) acc[i][j] = (frag_cd){0.f, 0.f, 0.f, 0.f};

  const bfu* Ag = A + (size_t)(m0 + sr) * 2048 + skc;
  const bfu* Bg = BT + (size_t)(n0 + sr) * 2048 + skc;
  bfu* Al = As + tid * 8;   // lane-linear: tid*16 bytes
  bfu* Bl = Bs + tid * 8;

  for (int k0 = 0; k0 < 2048; k0 += 32) {
    gl16(Ag + k0, Al);
    gl16(Ag + k0 + (size_t)64 * 2048, Al + 64 * 32);
    gl16(Bg + k0, Bl);
    gl16(Bg + k0 + (size_t)64 * 2048, Bl + 64 * 32);
    __syncthreads();  // compiler drains vmcnt before s_barrier
    frag_ab a[4], b[4];
#pragma unroll
    for (int im = 0; im < 4; ++im)
      a[im] = *(const frag_ab*)&As[(size_t)(wm + im * 16 + fm) * 32 + quad * 8];
#pragma unroll
    for (int in = 0; in < 4; ++in)
      b[in] = *(const frag_ab*)&Bs[(size_t)(wn + in * 16 + fm) * 32 + quad * 8];
#pragma unroll
    for (int im = 0; im < 4; ++im)
#pragma unroll
      for (int in = 0; in < 4; ++in)
        acc[im][in] = __builtin_amdgcn_mfma_f32_16x16x32_bf16(
            a[im], b[in], acc[im][in], 0, 0, 0);
    __syncthreads();
  }
#pragma unroll
  for (int im = 0; im < 4; ++im)
#pragma unroll
    for (int in = 0; in < 4; ++in) {
      const int n = n0 + wn + in * 16 + fm;
#pragma unroll
      for (int r = 0; r < 4; ++r) {
        const int m = m0 + wm + im * 16 + quad * 4 + r;
        C[(size_t)m * Nn + n] = acc[im][in][r];
      }
    }
}

// Fused Q/K/V projection: all three GEMMs in one 384-block dispatch.
__global__ __launch_bounds__(256) void gemm_qkv_k(
    const bfu* __restrict__ A, const bfu* __restrict__ BTq,
    const bfu* __restrict__ BTk, const bfu* __restrict__ BTv,
    float* __restrict__ Cq, float* __restrict__ Ck, float* __restrict__ Cv)
{
  __shared__ __align__(16) bfu As[128 * 32];
  __shared__ __align__(16) bfu Bs[128 * 32];
  int bx = blockIdx.x;
  const bfu* BT; float* C; int Nn;
  if (bx < 16)      { BT = BTq; C = Cq; Nn = 2048; }
  else if (bx < 20) { BT = BTk; C = Ck; Nn = 512; bx -= 16; }
  else              { BT = BTv; C = Cv; Nn = 512; bx -= 20; }
  gemm128_gl(A, BT, C, Nn, blockIdx.y * 128, bx * 128, As, Bs);
}

// Output projection GEMM.
__global__ __launch_bounds__(256) void gemm_wo_k(
    const bfu* __restrict__ A, const bfu* __restrict__ BT, float* __restrict__ C)
{
  __shared__ __align__(16) bfu As[128 * 32];
  __shared__ __align__(16) bfu Bs[128 * 32];
  gemm128_gl(A, BT, C, 2048, blockIdx.y * 128, blockIdx.x * 128, As, Bs);
}

// ---------------------------------------------------------------------------
// Per-row (64-wide) softmax of k -> kl, log_sigmoid(k)/16 -> gl, and
// k_bf = bf16(k) (pre-cast for the attention kernel).
// ---------------------------------------------------------------------------
__global__ __launch_bounds__(256) void gates64_k(
    const float* __restrict__ kin, float* __restrict__ kl, float* __restrict__ gl,
    bfu* __restrict__ k_bf)
{
  const int r = blockIdx.x * 4 + (threadIdx.x >> 6);
  const int lane = threadIdx.x & 63;
  const size_t idx = (size_t)r * 64 + lane;
  const float x = kin[idx];
  k_bf[idx] = f2bf(x);
  float m = x;
#pragma unroll
  for (int o = 32; o > 0; o >>= 1) m = fmaxf(m, __shfl_xor(m, o, 64));
  const float e = __expf(x - m);
  float s = e;
#pragma unroll
  for (int o = 32; o > 0; o >>= 1) s += __shfl_xor(s, o, 64);
  kl[idx] = e / s;
  const float ls = fminf(x, 0.f) - log1pf(__expf(-fabsf(x)));
  gl[idx] = ls * 0.0625f;
}

// ---------------------------------------------------------------------------
// Per (b,hkv,chunk): triangular solves.  256 blocks.
// L-matmul reads klT (b128); solve is BLOCKED forward substitution:
// 16-row diagonal blocks (serial, 128 thr) + trailing updates (all 256 thr).
// Ascending-j accumulation order preserved -> bitwise identical results.
// ---------------------------------------------------------------------------
__global__ __launch_bounds__(256) void chunk_prep_k(
    const float* __restrict__ kl, const float* __restrict__ v,
    const float* __restrict__ gl, float* __restrict__ u_out, float* __restrict__ w_out)
{
  __shared__ __align__(16) float KC[64][68];  // klT, then L
  __shared__ float KB[64][65];
  __shared__ float VB[64][65];
  const int blk = blockIdx.x;
  const int c = blk & 15, bh = blk >> 4;
  const int hk = bh & 7, b = bh >> 3;
  const int tid = threadIdx.x;
  for (int x = tid; x < 4096; x += 256) {
    const int i = x >> 6, d = x & 63;
    const size_t src = ((size_t)(b * Nc + c * 64 + i) * 8 + hk) * 64 + d;
    const float kv = kl[src], g = gl[src], vv = v[src];
    KC[d][i] = kv; KB[i][d] = kv * g; VB[i][d] = vv * g;
  }
  __syncthreads();
  // L[i][j] = sum_d KB[i][d] * kl[j][d], strictly lower.  Thread: (i, 16 j's).
  const int li = tid >> 2, j0 = (tid & 3) * 16;
  float acc[16];
#pragma unroll
  for (int jj = 0; jj < 16; ++jj) acc[jj] = 0.f;
  for (int d = 0; d < 64; ++d) {
    const float kb = KB[li][d];
    const float4 c0v = *(const float4*)&KC[d][j0];
    const float4 c1v = *(const float4*)&KC[d][j0 + 4];
    const float4 c2v = *(const float4*)&KC[d][j0 + 8];
    const float4 c3v = *(const float4*)&KC[d][j0 + 12];
    acc[0] += kb * c0v.x;  acc[1] += kb * c0v.y;  acc[2] += kb * c0v.z;  acc[3] += kb * c0v.w;
    acc[4] += kb * c1v.x;  acc[5] += kb * c1v.y;  acc[6] += kb * c1v.z;  acc[7] += kb * c1v.w;
    acc[8] += kb * c2v.x;  acc[9] += kb * c2v.y;  acc[10] += kb * c2v.z; acc[11] += kb * c2v.w;
    acc[12] += kb * c3v.x; acc[13] += kb * c3v.y; acc[14] += kb * c3v.z; acc[15] += kb * c3v.w;
  }
  __syncthreads();
#pragma unroll
  for (int jj = 0; jj < 16; ++jj)
    KC[li][j0 + jj] = (j0 + jj < li) ? acc[jj] : 0.f;
  __syncthreads();
  // Blocked forward substitution on X = [VB | KB] (unit lower L in KC).
  for (int r0 = 0; r0 < 64; r0 += 16) {
    if (r0 > 0) {
      // trailing update: X[r0+ii][d] -= sum_{j<r0} L[r0+ii][j] * X[j][d]
      for (int p = tid; p < 2048; p += 256) {
        const int ii = p >> 7, dc = p & 127;
        float (*X)[65] = (dc < 64) ? VB : KB;
        const int d = dc & 63;
        float a2 = X[r0 + ii][d];
        for (int j = 0; j < r0; ++j) a2 -= KC[r0 + ii][j] * X[j][d];
        X[r0 + ii][d] = a2;
      }
      __syncthreads();
    }
    // diagonal 16x16 solve (serial over rows, parallel over 128 cols)
    if (tid < 128) {
      const int d = tid & 63;
      float (*X)[65] = (tid < 64) ? VB : KB;
      for (int i = r0 + 1; i < r0 + 16; ++i) {
        float a2 = X[i][d];
        for (int j = r0; j < i; ++j) a2 -= KC[i][j] * X[j][d];
        X[i][d] = a2;
      }
    }
    __syncthreads();
  }
  for (int x = tid; x < 4096; x += 256) {
    u_out[(size_t)blk * 4096 + x] = VB[x >> 6][x & 63];
    w_out[(size_t)blk * 4096 + x] = KB[x >> 6][x & 63];
  }
}

// ---------------------------------------------------------------------------
// Serial scan over chunks per (b,hkv), COLUMN-SPLIT 4-ways.  64 blocks.
// ---------------------------------------------------------------------------
__global__ __launch_bounds__(256) void scan_k(
    const float* __restrict__ u_ps, const float* __restrict__ w_ps,
    const float* __restrict__ kl, float* __restrict__ u_p, float* __restrict__ S_pre)
{
  __shared__ __align__(16) float S[64][20];   // [e][c-slice]
  __shared__ __align__(16) float up[64][20];  // [i][c-slice]
  __shared__ __align__(16) float kw[64][68];  // w tile (full)
  __shared__ __align__(16) float kt[64][68];  // kl tile (full)
  const int blk = blockIdx.x;   // 64 blocks
  const int cg = blk & 3;       // column group (16 cols)
  const int bh = blk >> 2;
  const int hk = bh & 7, b = bh >> 3;
  const int t = threadIdx.x;    // 256
  const int row = t >> 2;       // 0..63
  const int c0 = (t & 3) * 4;   // 0,4,8,12 within slice
  const int cbase = cg * 16;    // global column offset
  for (int x = t; x < 1024; x += 256) S[x >> 4][x & 15] = 0.f;
  __syncthreads();
  for (int c = 0; c < 16; ++c) {
    const size_t cb = ((size_t)bh * 16 + c) * 4096;
    const float4 upre = *(const float4*)(u_ps + cb + row * 64 + cbase + c0);
    for (int x = t; x < 1024; x += 256) {
      const int i = x >> 4, d4 = (x & 15) * 4;
      *(float4*)&kw[i][d4] = *(const float4*)(w_ps + cb + i * 64 + d4);
      *(float4*)&kt[i][d4] =
          *(const float4*)(kl + ((size_t)(b * Nc + c * 64 + i) * 8 + hk) * 64 + d4);
    }
    for (int x = t; x < 1024; x += 256) {
      const int i = x >> 4, cc = x & 15;
      S_pre[cb + i * 64 + cbase + cc] = S[i][cc];
    }
    __syncthreads();
    {
      float a0 = upre.x, a1 = upre.y, a2 = upre.z, a3 = upre.w;
      for (int e4 = 0; e4 < 64; e4 += 4) {
        const float4 wv4 = *(const float4*)&kw[row][e4];
#pragma unroll
        for (int ee = 0; ee < 4; ++ee) {
          const float wv = ((const float*)&wv4)[ee];
          const float4 sv = *(const float4*)&S[e4 + ee][c0];
          a0 -= wv * sv.x; a1 -= wv * sv.y; a2 -= wv * sv.z; a3 -= wv * sv.w;
        }
      }
      const float4 o = make_float4(a0, a1, a2, a3);
      *(float4*)&up[row][c0] = o;
      *(float4*)(u_p + cb + row * 64 + cbase + c0) = o;
    }
    __syncthreads();
    {
      const float4 sv = *(const float4*)&S[row][c0];
      float s0 = sv.x, s1 = sv.y, s2 = sv.z, s3 = sv.w;
      for (int i = 0; i < 64; ++i) {
        const float kv = kt[i][row];
        const float4 uv = *(const float4*)&up[i][c0];
        s0 += kv * uv.x; s1 += kv * uv.y; s2 += kv * uv.z; s3 += kv * uv.w;
      }
      *(float4*)&S[row][c0] = make_float4(s0, s1, s2, s3);
    }
    __syncthreads();
  }
}

// ---------------------------------------------------------------------------
// o_lin per (b,h,chunk).  1024 blocks.  Also emits q_bf = bf16(q_raw)
// (it reads every q element once during staging; removes the cast dispatch).
// Phases 2/3 read Bb via float4 (b128).
// ---------------------------------------------------------------------------
__global__ __launch_bounds__(256) void olin_k(
    const float* __restrict__ qraw, const float* __restrict__ kl,
    const float* __restrict__ upb, const float* __restrict__ S_pre,
    float* __restrict__ o_comb, bfu* __restrict__ q_bf)
{
  __shared__ float Q[64][65];
  __shared__ __align__(16) float Bb[64][68];
  __shared__ float At[64][65];
  const int blk = blockIdx.x;
  const int c = blk & 15, bh = blk >> 4;
  const int h = bh & 31, b = bh >> 5, hk = h >> 2;
  const int tid = threadIdx.x;
  const int i = tid >> 2, d0 = (tid & 3) * 16;
  for (int x = tid; x < 4096; x += 256) {
    const int r = x >> 6, d = x & 63;
    const size_t qidx = ((size_t)(b * Nc + c * 64 + r) * 32 + h) * 64 + d;
    const float qv = qraw[qidx];
    Q[r][d] = qv;
    q_bf[qidx] = f2bf(qv);
    Bb[d][r] = kl[((size_t)(b * Nc + c * 64 + r) * 8 + hk) * 64 + d];  // klT
  }
  __syncthreads();
  {
    float mx = -1e30f;
#pragma unroll
    for (int j = 0; j < 16; ++j) mx = fmaxf(mx, Q[i][d0 + j]);
#pragma unroll
    for (int o = 1; o < 4; o <<= 1) mx = fmaxf(mx, __shfl_xor(mx, o, 64));
    float ev[16];
    float sum = 0.f;
#pragma unroll
    for (int j = 0; j < 16; ++j) { ev[j] = __expf(Q[i][d0 + j] - mx); sum += ev[j]; }
#pragma unroll
    for (int o = 1; o < 4; o <<= 1) sum += __shfl_xor(sum, o, 64);
    const float inv = 1.f / sum;
#pragma unroll
    for (int j = 0; j < 16; ++j) Q[i][d0 + j] = ev[j] * inv;
  }
  __syncthreads();
  {
    // At[i][d0+j] = sum_d Q[i][d] * klT[d][d0+j]   (b128 reads of Bb rows)
    float a[16];
#pragma unroll
    for (int j = 0; j < 16; ++j) a[j] = 0.f;
    for (int d = 0; d < 64; ++d) {
      const float qv = Q[i][d];
      const float4 b0 = *(const float4*)&Bb[d][d0];
      const float4 b1 = *(const float4*)&Bb[d][d0 + 4];
      const float4 b2 = *(const float4*)&Bb[d][d0 + 8];
      const float4 b3 = *(const float4*)&Bb[d][d0 + 12];
      a[0] += qv * b0.x;  a[1] += qv * b0.y;  a[2] += qv * b0.z;  a[3] += qv * b0.w;
      a[4] += qv * b1.x;  a[5] += qv * b1.y;  a[6] += qv * b1.z;  a[7] += qv * b1.w;
      a[8] += qv * b2.x;  a[9] += qv * b2.y;  a[10] += qv * b2.z; a[11] += qv * b2.w;
      a[12] += qv * b3.x; a[13] += qv * b3.y; a[14] += qv * b3.z; a[15] += qv * b3.w;
    }
#pragma unroll
    for (int j = 0; j < 16; ++j) At[i][d0 + j] = (d0 + j <= i) ? a[j] : 0.f;
  }
  __syncthreads();
  const size_t cb = ((size_t)(b * 8 + hk) * 16 + c) * 4096;
  for (int x = tid; x < 4096; x += 256) Bb[x >> 6][x & 63] = S_pre[cb + x];
  __syncthreads();
  float o[16];
#pragma unroll
  for (int j = 0; j < 16; ++j) o[j] = 0.f;
  for (int e = 0; e < 64; ++e) {
    const float qv = Q[i][e];
    const float4 b0 = *(const float4*)&Bb[e][d0];
    const float4 b1 = *(const float4*)&Bb[e][d0 + 4];
    const float4 b2 = *(const float4*)&Bb[e][d0 + 8];
    const float4 b3 = *(const float4*)&Bb[e][d0 + 12];
    o[0] += qv * b0.x;  o[1] += qv * b0.y;  o[2] += qv * b0.z;  o[3] += qv * b0.w;
    o[4] += qv * b1.x;  o[5] += qv * b1.y;  o[6] += qv * b1.z;  o[7] += qv * b1.w;
    o[8] += qv * b2.x;  o[9] += qv * b2.y;  o[10] += qv * b2.z; o[11] += qv * b2.w;
    o[12] += qv * b3.x; o[13] += qv * b3.y; o[14] += qv * b3.z; o[15] += qv * b3.w;
  }
  __syncthreads();
  for (int x = tid; x < 4096; x += 256) Bb[x >> 6][x & 63] = upb[cb + x];
  __syncthreads();
  for (int j2 = 0; j2 < 64; ++j2) {
    const float av = At[i][j2];
    const float4 b0 = *(const float4*)&Bb[j2][d0];
    const float4 b1 = *(const float4*)&Bb[j2][d0 + 4];
    const float4 b2 = *(const float4*)&Bb[j2][d0 + 8];
    const float4 b3 = *(const float4*)&Bb[j2][d0 + 12];
    o[0] += av * b0.x;  o[1] += av * b0.y;  o[2] += av * b0.z;  o[3] += av * b0.w;
    o[4] += av * b1.x;  o[5] += av * b1.y;  o[6] += av * b1.z;  o[7] += av * b1.w;
    o[8] += av * b2.x;  o[9] += av * b2.y;  o[10] += av * b2.z; o[11] += av * b2.w;
    o[12] += av * b3.x; o[13] += av * b3.y; o[14] += av * b3.z; o[15] += av * b3.w;
  }
  float* oc = o_comb + ((size_t)(b * Nc + c * 64 + i) * 32 + h) * 64 + d0;
#pragma unroll
  for (int j = 0; j < 16; ++j) oc[j] = 0.5f * o[j];
}

// ---------------------------------------------------------------------------
// Tile-copy helper: 64x64 bf16 tile global -> LDS [row][LDK], 2 uint4/thread.
// ---------------------------------------------------------------------------
template <int LDK>
__device__ __forceinline__ void stage_tile(
    const bfu* __restrict__ g, size_t row_stride, bfu* dst, int tid)
{
  const int xr = tid >> 3;         // 0..31
  const int xc = (tid & 7) * 8;    // 0,8,..,56
#pragma unroll
  for (int hh = 0; hh < 2; ++hh) {
    const int row = xr + hh * 32;
    *(uint4*)&dst[(size_t)row * LDK + xc] =
        *(const uint4*)(g + (size_t)row * row_stride + xc);
  }
}

// ---------------------------------------------------------------------------
// FUSED base attention (MFMA): pass 1 online m,l over K tiles jt<=ib (these
// depend only on this block's tiles); in-LDS reduce to final M,L; pass 2
// recomputes scores, writes attn p-values, and accumulates PV.  Writes
// oc_bf = bf16(o_comb + 0.5*o_base).  1024 blocks x 256 threads.
// Replaces the ml_mfma_k + pv_mfma_k pair (same math, same order).
// ---------------------------------------------------------------------------
__global__ __launch_bounds__(256) void attn_mfma_k(
    const bfu* __restrict__ qbf, const bfu* __restrict__ kbf,
    const bfu* __restrict__ vtbf, float* __restrict__ attn,
    const float* __restrict__ o_comb, bfu* __restrict__ oc_bf)
{
  constexpr int LDK = 72;
  __shared__ __align__(16) bfu Qt[64 * LDK];    // [i][d]
  __shared__ __align__(16) bfu Kt[64 * LDK];    // [j][d]
  __shared__ __align__(16) bfu Vt[64 * LDK];    // [dv][j]
  __shared__ __align__(16) bfu Pmat[64 * LDK];  // [i][j]
  __shared__ float mred[4][64];
  __shared__ float lred[4][64];
  __shared__ float mfin[64];
  __shared__ float lfin[64];
  const int blk = blockIdx.x;
  const int ib = blk & 15, bh = blk >> 4;
  const int h = bh & 31, b = bh >> 5, hk = h >> 2;
  const int tid = threadIdx.x;
  const int wave = tid >> 6, lane = tid & 63;
  const int fm = lane & 15, quad = lane >> 4;
  const int wj = wave * 16;   // score phase: wave's j slice
  const int im0 = wave * 16;  // PV phase: wave's i slice

  stage_tile<LDK>(qbf + ((size_t)(b * Nc + ib * 64) * 32 + h) * 64,
                  (size_t)32 * 64, Qt, tid);
  __syncthreads();
  frag_ab qb[4][2];
#pragma unroll
  for (int in = 0; in < 4; ++in)
#pragma unroll
    for (int kk = 0; kk < 2; ++kk)
      qb[in][kk] = *(const frag_ab*)&Qt[(size_t)(in * 16 + fm) * LDK + kk * 32 + quad * 8];

  // ---- pass 1: online m,l ----
  float m[4], l[4];
#pragma unroll
  for (int in = 0; in < 4; ++in) { m[in] = -1e30f; l[in] = 0.f; }

  for (int jt = 0; jt <= ib; ++jt) {
    __syncthreads();
    stage_tile<LDK>(kbf + ((size_t)(b * Nc + jt * 64) * 8 + hk) * 64,
                    (size_t)8 * 64, Kt, tid);
    __syncthreads();
    frag_ab ka[2];
    ka[0] = *(const frag_ab*)&Kt[(size_t)(wj + fm) * LDK + quad * 8];
    ka[1] = *(const frag_ab*)&Kt[(size_t)(wj + fm) * LDK + 32 + quad * 8];
    const bool diag = (jt == ib);
#pragma unroll
    for (int in = 0; in < 4; ++in) {
      frag_cd acc = (frag_cd){0.f, 0.f, 0.f, 0.f};
      acc = __builtin_amdgcn_mfma_f32_16x16x32_bf16(ka[0], qb[in][0], acc, 0, 0, 0);
      acc = __builtin_amdgcn_mfma_f32_16x16x32_bf16(ka[1], qb[in][1], acc, 0, 0, 0);
      const int iloc = in * 16 + fm;
      float sv[4];
      bool vd[4];
      float tm = -1e30f;
#pragma unroll
      for (int r = 0; r < 4; ++r) {
        const int jloc = wj + quad * 4 + r;
        vd[r] = !diag || (jloc <= iloc);
        sv[r] = acc[r] * 0.125f;
        if (vd[r]) tm = fmaxf(tm, sv[r]);
      }
      const float mn = fmaxf(m[in], tm);
      float lsum = 0.f;
#pragma unroll
      for (int r = 0; r < 4; ++r)
        if (vd[r]) lsum += __expf(sv[r] - mn);
      l[in] = l[in] * __expf(m[in] - mn) + lsum;  // l==0 when m==-1e30, safe
      m[in] = mn;
    }
  }
  // reduce across quads then waves (same order as the two-kernel version)
#pragma unroll
  for (int in = 0; in < 4; ++in) {
    float mm = m[in], ll = l[in];
#pragma unroll
    for (int off = 16; off < 64; off <<= 1) {
      const float mo = __shfl_xor(mm, off, 64);
      const float lo = __shfl_xor(ll, off, 64);
      const float mn = fmaxf(mm, mo);
      ll = ll * __expf(mm - mn) + lo * __expf(mo - mn);
      mm = mn;
    }
    if (quad == 0) { mred[wave][in * 16 + fm] = mm; lred[wave][in * 16 + fm] = ll; }
  }
  __syncthreads();
  if (tid < 64) {
    float M = -1e30f;
#pragma unroll
    for (int w = 0; w < 4; ++w) M = fmaxf(M, mred[w][tid]);
    float L = 0.f;
#pragma unroll
    for (int w = 0; w < 4; ++w) L += lred[w][tid] * __expf(mred[w][tid] - M);
    mfin[tid] = M;
    lfin[tid] = L;
  }
  __syncthreads();
  float mi[4], il[4];
#pragma unroll
  for (int in = 0; in < 4; ++in) {
    mi[in] = mfin[in * 16 + fm];
    il[in] = 1.f / lfin[in * 16 + fm];
  }

  // ---- pass 2: p-write + PV ----
  float* arow0 = attn + ((size_t)(b * 32 + h) * 1024 + ib * 64) * 1024;
  frag_cd o[4];
#pragma unroll
  for (int in = 0; in < 4; ++in) o[in] = (frag_cd){0.f, 0.f, 0.f, 0.f};

  for (int jt = 0; jt <= ib; ++jt) {
    __syncthreads();  // protect prev iter's Vt/Pmat reads (and mfin/lfin)
    stage_tile<LDK>(kbf + ((size_t)(b * Nc + jt * 64) * 8 + hk) * 64,
                    (size_t)8 * 64, Kt, tid);
    stage_tile<LDK>(vtbf + (size_t)(b * 8 + hk) * 64 * 1024 + jt * 64,
                    (size_t)1024, Vt, tid);
    __syncthreads();
    frag_ab ka[2];
    ka[0] = *(const frag_ab*)&Kt[(size_t)(wj + fm) * LDK + quad * 8];
    ka[1] = *(const frag_ab*)&Kt[(size_t)(wj + fm) * LDK + 32 + quad * 8];
    const bool diag = (jt == ib);
#pragma unroll
    for (int in = 0; in < 4; ++in) {
      frag_cd acc = (frag_cd){0.f, 0.f, 0.f, 0.f};
      acc = __builtin_amdgcn_mfma_f32_16x16x32_bf16(ka[0], qb[in][0], acc, 0, 0, 0);
      acc = __builtin_amdgcn_mfma_f32_16x16x32_bf16(ka[1], qb[in][1], acc, 0, 0, 0);
      const int iloc = in * 16 + fm;
      float p[4];
#pragma unroll
      for (int r = 0; r < 4; ++r) {
        const int jloc = wj + quad * 4 + r;
        const bool vdr = !diag || (jloc <= iloc);
        p[r] = vdr ? __expf(acc[r] * 0.125f - mi[in]) * il[in] : 0.f;
      }
      *(float4*)(arow0 + (size_t)iloc * 1024 + jt * 64 + wj + quad * 4) =
          make_float4(p[0], p[1], p[2], p[3]);
      ushort4 w;
      w.x = f2bf(p[0]); w.y = f2bf(p[1]); w.z = f2bf(p[2]); w.w = f2bf(p[3]);
      *(ushort4*)&Pmat[(size_t)iloc * LDK + wj + quad * 4] = w;
    }
    __syncthreads();
    frag_ab pa[2];
    pa[0] = *(const frag_ab*)&Pmat[(size_t)(im0 + fm) * LDK + quad * 8];
    pa[1] = *(const frag_ab*)&Pmat[(size_t)(im0 + fm) * LDK + 32 + quad * 8];
#pragma unroll
    for (int in = 0; in < 4; ++in) {
      frag_ab vb0 = *(const frag_ab*)&Vt[(size_t)(in * 16 + fm) * LDK + quad * 8];
      frag_ab vb1 = *(const frag_ab*)&Vt[(size_t)(in * 16 + fm) * LDK + 32 + quad * 8];
      o[in] = __builtin_amdgcn_mfma_f32_16x16x32_bf16(pa[0], vb0, o[in], 0, 0, 0);
      o[in] = __builtin_amdgcn_mfma_f32_16x16x32_bf16(pa[1], vb1, o[in], 0, 0, 0);
    }
  }
  // zero-fill non-causal tiles of attn
  for (int jt2 = ib + 1; jt2 < 16; ++jt2) {
    const float4 z = make_float4(0.f, 0.f, 0.f, 0.f);
    for (int x = tid; x < 1024; x += 256) {
      const int row = x >> 4, c4 = (x & 15) * 4;
      *(float4*)(arow0 + (size_t)row * 1024 + jt2 * 64 + c4) = z;
    }
  }
  // oc_bf = bf16(o_comb + 0.5*o)
#pragma unroll
  for (int in = 0; in < 4; ++in)
#pragma unroll
    for (int r = 0; r < 4; ++r) {
      const int i = im0 + quad * 4 + r;
      const size_t idx = ((size_t)(b * Nc + ib * 64 + i) * 32 + h) * 64 + in * 16 + fm;
      oc_bf[idx] = f2bf(o_comb[idx] + 0.5f * o[in][r]);
    }
}

// ---------------------------------------------------------------------------
extern "C" void kernel_launch(void* const* d_in, const int* in_sizes, int n_in,
                              void* d_out, int out_size, void* d_ws, size_t ws_size,
                              hipStream_t stream) {
  const float* hs = (const float*)d_in[0];
  const float* Wq = (const float*)d_in[1];
  const float* Wk = (const float*)d_in[2];
  const float* Wv = (const float*)d_in[3];
  const float* Wo = (const float*)d_in[4];
  float* out = (float*)d_out;                      // [B,N,HID]
  float* attn = out + (size_t)Bc * Nc * HIDc;      // [B,H,N,N]

  float* ws = (float*)d_ws;
  float* q_raw  = ws;                     // 4,194,304 f32
  float* k_raw  = q_raw + 4194304;        // 1,048,576
  float* v_raw  = k_raw + 1048576;        // 1,048,576
  float* kl     = v_raw + 1048576;        // 1,048,576
  float* gl     = kl + 1048576;           // 1,048,576
  float* u_ps   = gl + 1048576;           // 2,097,152
  float* w_ps   = u_ps + 2097152;         // 2,097,152
  float* upb    = w_ps + 2097152;         // 2,097,152
  float* S_pre  = upb + 2097152;          // 2,097,152
  float* o_comb = S_pre + 2097152;        // 4,194,304
  float* mbuf   = o_comb + 4194304;       // 65,536 (unused, layout kept)
  float* lbuf   = mbuf + 65536;           // 65,536 (unused, layout kept)
  bfu* bstart = (bfu*)(lbuf + 65536);
  bfu* hs_bf  = bstart;                   // 4,194,304 bf16
  bfu* WqT    = hs_bf + 4194304;          // 4,194,304
  bfu* WkT    = WqT + 4194304;            // 1,048,576
  bfu* WvT    = WkT + 1048576;            // 1,048,576
  bfu* WoT    = WvT + 1048576;            // 4,194,304
  bfu* oc_bf  = WoT + 4194304;            // 4,194,304
  // Aliases of regions dead after gemm_qkv_k (stream-ordered, safe):
  bfu* q_bf   = hs_bf;                    // 4,194,304 bf16 (aliases hs_bf)
  bfu* k_bf   = WqT;                      // 1,048,576 bf16 (aliases WqT)
  bfu* vt_bf  = WqT + 1048576;            // 1,048,576 bf16 (aliases WqT+1M)

  // Casts / weight transposes
  cast_bf16_k<<<4096, 256, 0, stream>>>(hs, hs_bf);
  transpose_cast_k<<<dim3(64, 64), 256, 0, stream>>>(Wq, WqT, 2048, 2048);
  transpose_cast_k<<<dim3(16, 64), 256, 0, stream>>>(Wk, WkT, 2048, 512);
  transpose_cast_k<<<dim3(16, 64), 256, 0, stream>>>(Wv, WvT, 2048, 512);
  transpose_cast_k<<<dim3(64, 64), 256, 0, stream>>>(Wo, WoT, 2048, 2048);
  // Fused Q/K/V projection (bf16 MFMA, global_load_lds staging, 384 blocks)
  gemm_qkv_k<<<dim3(24, 16), 256, 0, stream>>>(hs_bf, WqT, WkT, WvT,
                                               q_raw, k_raw, v_raw);
  // Gates (also emits k_bf); V transpose (emits vt_bf)
  gates64_k<<<4096, 256, 0, stream>>>(k_raw, kl, gl, k_bf);
  transpose_v_k<<<256, 256, 0, stream>>>(v_raw, vt_bf);
  // Delta-rule
  chunk_prep_k<<<256, 256, 0, stream>>>(kl, v_raw, gl, u_ps, w_ps);
  scan_k<<<64, 256, 0, stream>>>(u_ps, w_ps, kl, upb, S_pre);
  // Linear-attention output (writes o_comb = 0.5*o_lin AND q_bf)
  olin_k<<<1024, 256, 0, stream>>>(q_raw, kl, upb, S_pre, o_comb, q_bf);
  // Fused base causal attention (m,l pass + p/attn-write/PV pass in one)
  attn_mfma_k<<<1024, 256, 0, stream>>>(q_bf, k_bf, vt_bf, attn, o_comb, oc_bf);
  // Output projection (reads bf16 written by attn_mfma_k)
  gemm_wo_k<<<dim3(16, 16), 256, 0, stream>>>(oc_bf, WoT, out);
}

// Round 8
// 636.245 us; speedup vs baseline: 1.2205x; 1.0231x over previous
//
#include <hip/hip_runtime.h>
#include <hip/hip_bf16.h>

// Problem constants
constexpr int Bc = 2, Nc = 1024, HIDc = 2048, Hc = 32, Dc = 64, HKVc = 8, NCc = 16;

typedef unsigned short bfu;  // raw bf16 bits
typedef __attribute__((ext_vector_type(8))) short frag_ab;  // 8 bf16 (4 VGPRs)
typedef __attribute__((ext_vector_type(4))) float frag_cd;  // 4 fp32 acc

__device__ __forceinline__ bfu f2bf(float f) {
  unsigned int u = __float_as_uint(f);
  unsigned int r = u + 0x7fffu + ((u >> 16) & 1u);  // RNE
  return (bfu)(r >> 16);
}
__device__ __forceinline__ ushort4 pack4(float4 v) {
  ushort4 r; r.x = f2bf(v.x); r.y = f2bf(v.y); r.z = f2bf(v.z); r.w = f2bf(v.w);
  return r;
}

// async global->LDS, 16B per lane (m97 pattern: lane-linear staging layout)
__device__ __forceinline__ void gl16(const bfu* g, bfu* l) {
  __builtin_amdgcn_global_load_lds(
      (const __attribute__((address_space(1))) void*)g,
      (__attribute__((address_space(3))) void*)l, 16, 0, 0);
}

// ---------------------------------------------------------------------------
// Fused prep: hs fp32->bf16 flat cast (blocks 0..4095) + 4 weight
// transpose-casts W[K][N] -> WT[N][K] (blocks 4096..14335).  One dispatch
// replaces five (launch-overhead removal; bodies identical to before).
// ---------------------------------------------------------------------------
__global__ __launch_bounds__(256) void prep_k(
    const float* __restrict__ hs, bfu* __restrict__ hs_bf,
    const float* __restrict__ Wq, bfu* __restrict__ WqT,
    const float* __restrict__ Wk, bfu* __restrict__ WkT,
    const float* __restrict__ Wv, bfu* __restrict__ WvT,
    const float* __restrict__ Wo, bfu* __restrict__ WoT)
{
  __shared__ float t[32][33];
  int bx = blockIdx.x;
  if (bx < 4096) {  // flat cast of hs
    const size_t i = ((size_t)bx * 256 + threadIdx.x) * 4;
    *(ushort4*)(hs_bf + i) = pack4(*(const float4*)(hs + i));
    return;  // uniform per-block exit: no barrier crossed
  }
  bx -= 4096;
  const float* W; bfu* WT; int K, N, nb;
  if (bx < 4096)      { W = Wq; WT = WqT; K = 2048; N = 2048; nb = 64; }
  else if (bx < 5120) { W = Wk; WT = WkT; K = 2048; N = 512;  nb = 16; bx -= 4096; }
  else if (bx < 6144) { W = Wv; WT = WvT; K = 2048; N = 512;  nb = 16; bx -= 5120; }
  else                { W = Wo; WT = WoT; K = 2048; N = 2048; nb = 64; bx -= 6144; }
  const int bn = (bx % nb) * 32, bk = (bx / nb) * 32;
  const int x = threadIdx.x & 31, y = threadIdx.x >> 5;  // 32x8
#pragma unroll
  for (int i = 0; i < 32; i += 8)
    t[y + i][x] = W[(size_t)(bk + y + i) * N + bn + x];
  __syncthreads();
#pragma unroll
  for (int i = 0; i < 32; i += 8)
    WT[(size_t)(bn + y + i) * K + bk + x] = f2bf(t[x][y + i]);
}

// ---------------------------------------------------------------------------
// V transpose + cast: v fp32 [b,n,hk,dv] -> vt bf16 [b,hk,dv,n].  256 blocks.
// ---------------------------------------------------------------------------
__global__ __launch_bounds__(256) void transpose_v_k(
    const float* __restrict__ v, bfu* __restrict__ vt)
{
  __shared__ __align__(16) bfu T[64][72];
  const int blk = blockIdx.x;
  const int nt = blk & 15, bh = blk >> 4;  // n-tile, b*8+hk
  const int hk = bh & 7, b = bh >> 3;
  const int tid = threadIdx.x;
  const int n = tid >> 2, dv0 = (tid & 3) * 16;
  const float* src = v + ((size_t)(b * Nc + nt * 64 + n) * 8 + hk) * 64 + dv0;
#pragma unroll
  for (int e = 0; e < 16; ++e) T[dv0 + e][n] = f2bf(src[e]);
  __syncthreads();
  const int r = tid >> 3, c = (tid & 7) * 8;
#pragma unroll
  for (int hh = 0; hh < 2; ++hh) {
    const int dv = r + hh * 32;
    *(uint4*)(vt + ((size_t)(bh * 64 + dv)) * 1024 + nt * 64 + c) =
        *(const uint4*)&T[dv][c];
  }
}

// ---------------------------------------------------------------------------
// Shared MFMA GEMM body (m97 structure): A bf16 [M][2048] x BT bf16 [N][2048]
// -> C fp32 [M][Nn].  128x128 tile, BK=32, 256 thr (4 waves 2x2), linear LDS,
// global_load_lds dwordx4 staging.
// ---------------------------------------------------------------------------
__device__ __forceinline__ void gemm128_gl(
    const bfu* __restrict__ A, const bfu* __restrict__ BT,
    float* __restrict__ C, const int Nn, const int m0, const int n0,
    bfu* As, bfu* Bs)
{
  const int tid = threadIdx.x;
  const int wave = tid >> 6, lane = tid & 63;
  const int wm = (wave >> 1) * 64, wn = (wave & 1) * 64;
  const int fm = lane & 15, quad = lane >> 4;
  const int sr = tid >> 2, skc = (tid & 3) * 8;  // staging row / k-col

  frag_cd acc[4][4];
#pragma unroll
  for (int i = 0; i < 4; ++i)
#pragma unroll
    for (int j = 0; j < 4; ++j) acc[i][j] = (frag_cd){0.f, 0.f, 0.f, 0.f};

  const bfu* Ag = A + (size_t)(m0 + sr) * 2048 + skc;
  const bfu* Bg = BT + (size_t)(n0 + sr) * 2048 + skc;
  bfu* Al = As + tid * 8;   // lane-linear: tid*16 bytes
  bfu* Bl = Bs + tid * 8;

  for (int k0 = 0; k0 < 2048; k0 += 32) {
    gl16(Ag + k0, Al);
    gl16(Ag + k0 + (size_t)64 * 2048, Al + 64 * 32);
    gl16(Bg + k0, Bl);
    gl16(Bg + k0 + (size_t)64 * 2048, Bl + 64 * 32);
    __syncthreads();  // compiler drains vmcnt before s_barrier
    frag_ab a[4], b[4];
#pragma unroll
    for (int im = 0; im < 4; ++im)
      a[im] = *(const frag_ab*)&As[(size_t)(wm + im * 16 + fm) * 32 + quad * 8];
#pragma unroll
    for (int in = 0; in < 4; ++in)
      b[in] = *(const frag_ab*)&Bs[(size_t)(wn + in * 16 + fm) * 32 + quad * 8];
#pragma unroll
    for (int im = 0; im < 4; ++im)
#pragma unroll
      for (int in = 0; in < 4; ++in)
        acc[im][in] = __builtin_amdgcn_mfma_f32_16x16x32_bf16(
            a[im], b[in], acc[im][in], 0, 0, 0);
    __syncthreads();
  }
#pragma unroll
  for (int im = 0; im < 4; ++im)
#pragma unroll
    for (int in = 0; in < 4; ++in) {
      const int n = n0 + wn + in * 16 + fm;
#pragma unroll
      for (int r = 0; r < 4; ++r) {
        const int m = m0 + wm + im * 16 + quad * 4 + r;
        C[(size_t)m * Nn + n] = acc[im][in][r];
      }
    }
}

// Fused Q/K/V projection: all three GEMMs in one 384-block dispatch.
__global__ __launch_bounds__(256) void gemm_qkv_k(
    const bfu* __restrict__ A, const bfu* __restrict__ BTq,
    const bfu* __restrict__ BTk, const bfu* __restrict__ BTv,
    float* __restrict__ Cq, float* __restrict__ Ck, float* __restrict__ Cv)
{
  __shared__ __align__(16) bfu As[128 * 32];
  __shared__ __align__(16) bfu Bs[128 * 32];
  int bx = blockIdx.x;
  const bfu* BT; float* C; int Nn;
  if (bx < 16)      { BT = BTq; C = Cq; Nn = 2048; }
  else if (bx < 20) { BT = BTk; C = Ck; Nn = 512; bx -= 16; }
  else              { BT = BTv; C = Cv; Nn = 512; bx -= 20; }
  gemm128_gl(A, BT, C, Nn, blockIdx.y * 128, bx * 128, As, Bs);
}

// Output projection GEMM.
__global__ __launch_bounds__(256) void gemm_wo_k(
    const bfu* __restrict__ A, const bfu* __restrict__ BT, float* __restrict__ C)
{
  __shared__ __align__(16) bfu As[128 * 32];
  __shared__ __align__(16) bfu Bs[128 * 32];
  gemm128_gl(A, BT, C, 2048, blockIdx.y * 128, blockIdx.x * 128, As, Bs);
}

// ---------------------------------------------------------------------------
// Per-row (64-wide) softmax of k -> kl, log_sigmoid(k)/16 -> gl, and
// k_bf = bf16(k) (pre-cast for the attention kernel).
// ---------------------------------------------------------------------------
__global__ __launch_bounds__(256) void gates64_k(
    const float* __restrict__ kin, float* __restrict__ kl, float* __restrict__ gl,
    bfu* __restrict__ k_bf)
{
  const int r = blockIdx.x * 4 + (threadIdx.x >> 6);
  const int lane = threadIdx.x & 63;
  const size_t idx = (size_t)r * 64 + lane;
  const float x = kin[idx];
  k_bf[idx] = f2bf(x);
  float m = x;
#pragma unroll
  for (int o = 32; o > 0; o >>= 1) m = fmaxf(m, __shfl_xor(m, o, 64));
  const float e = __expf(x - m);
  float s = e;
#pragma unroll
  for (int o = 32; o > 0; o >>= 1) s += __shfl_xor(s, o, 64);
  kl[idx] = e / s;
  const float ls = fminf(x, 0.f) - log1pf(__expf(-fabsf(x)));
  gl[idx] = ls * 0.0625f;
}

// ---------------------------------------------------------------------------
// Per (b,hkv,chunk): triangular solves.  256 blocks.
// ---------------------------------------------------------------------------
__global__ __launch_bounds__(256) void chunk_prep_k(
    const float* __restrict__ kl, const float* __restrict__ v,
    const float* __restrict__ gl, float* __restrict__ u_out, float* __restrict__ w_out)
{
  __shared__ __align__(16) float KC[64][68];  // klT, then L
  __shared__ float KB[64][65];
  __shared__ float VB[64][65];
  const int blk = blockIdx.x;
  const int c = blk & 15, bh = blk >> 4;
  const int hk = bh & 7, b = bh >> 3;
  const int tid = threadIdx.x;
  for (int x = tid; x < 4096; x += 256) {
    const int i = x >> 6, d = x & 63;
    const size_t src = ((size_t)(b * Nc + c * 64 + i) * 8 + hk) * 64 + d;
    const float kv = kl[src], g = gl[src], vv = v[src];
    KC[d][i] = kv; KB[i][d] = kv * g; VB[i][d] = vv * g;
  }
  __syncthreads();
  // L[i][j] = sum_d KB[i][d] * kl[j][d], strictly lower.  Thread: (i, 16 j's).
  const int li = tid >> 2, j0 = (tid & 3) * 16;
  float acc[16];
#pragma unroll
  for (int jj = 0; jj < 16; ++jj) acc[jj] = 0.f;
  for (int d = 0; d < 64; ++d) {
    const float kb = KB[li][d];
    const float4 c0v = *(const float4*)&KC[d][j0];
    const float4 c1v = *(const float4*)&KC[d][j0 + 4];
    const float4 c2v = *(const float4*)&KC[d][j0 + 8];
    const float4 c3v = *(const float4*)&KC[d][j0 + 12];
    acc[0] += kb * c0v.x;  acc[1] += kb * c0v.y;  acc[2] += kb * c0v.z;  acc[3] += kb * c0v.w;
    acc[4] += kb * c1v.x;  acc[5] += kb * c1v.y;  acc[6] += kb * c1v.z;  acc[7] += kb * c1v.w;
    acc[8] += kb * c2v.x;  acc[9] += kb * c2v.y;  acc[10] += kb * c2v.z; acc[11] += kb * c2v.w;
    acc[12] += kb * c3v.x; acc[13] += kb * c3v.y; acc[14] += kb * c3v.z; acc[15] += kb * c3v.w;
  }
  __syncthreads();
#pragma unroll
  for (int jj = 0; jj < 16; ++jj)
    KC[li][j0 + jj] = (j0 + jj < li) ? acc[jj] : 0.f;
  __syncthreads();
  // Blocked forward substitution on X = [VB | KB] (unit lower L in KC).
  for (int r0 = 0; r0 < 64; r0 += 16) {
    if (r0 > 0) {
      for (int p = tid; p < 2048; p += 256) {
        const int ii = p >> 7, dc = p & 127;
        float (*X)[65] = (dc < 64) ? VB : KB;
        const int d = dc & 63;
        float a2 = X[r0 + ii][d];
        for (int j = 0; j < r0; ++j) a2 -= KC[r0 + ii][j] * X[j][d];
        X[r0 + ii][d] = a2;
      }
      __syncthreads();
    }
    if (tid < 128) {
      const int d = tid & 63;
      float (*X)[65] = (tid < 64) ? VB : KB;
      for (int i = r0 + 1; i < r0 + 16; ++i) {
        float a2 = X[i][d];
        for (int j = r0; j < i; ++j) a2 -= KC[i][j] * X[j][d];
        X[i][d] = a2;
      }
    }
    __syncthreads();
  }
  for (int x = tid; x < 4096; x += 256) {
    u_out[(size_t)blk * 4096 + x] = VB[x >> 6][x & 63];
    w_out[(size_t)blk * 4096 + x] = KB[x >> 6][x & 63];
  }
}

// ---------------------------------------------------------------------------
// Serial scan over chunks per (b,hkv), COLUMN-SPLIT 4-ways.  64 blocks.
// ---------------------------------------------------------------------------
__global__ __launch_bounds__(256) void scan_k(
    const float* __restrict__ u_ps, const float* __restrict__ w_ps,
    const float* __restrict__ kl, float* __restrict__ u_p, float* __restrict__ S_pre)
{
  __shared__ __align__(16) float S[64][20];   // [e][c-slice]
  __shared__ __align__(16) float up[64][20];  // [i][c-slice]
  __shared__ __align__(16) float kw[64][68];  // w tile (full)
  __shared__ __align__(16) float kt[64][68];  // kl tile (full)
  const int blk = blockIdx.x;   // 64 blocks
  const int cg = blk & 3;       // column group (16 cols)
  const int bh = blk >> 2;
  const int hk = bh & 7, b = bh >> 3;
  const int t = threadIdx.x;    // 256
  const int row = t >> 2;       // 0..63
  const int c0 = (t & 3) * 4;   // 0,4,8,12 within slice
  const int cbase = cg * 16;    // global column offset
  for (int x = t; x < 1024; x += 256) S[x >> 4][x & 15] = 0.f;
  __syncthreads();
  for (int c = 0; c < 16; ++c) {
    const size_t cb = ((size_t)bh * 16 + c) * 4096;
    const float4 upre = *(const float4*)(u_ps + cb + row * 64 + cbase + c0);
    for (int x = t; x < 1024; x += 256) {
      const int i = x >> 4, d4 = (x & 15) * 4;
      *(float4*)&kw[i][d4] = *(const float4*)(w_ps + cb + i * 64 + d4);
      *(float4*)&kt[i][d4] =
          *(const float4*)(kl + ((size_t)(b * Nc + c * 64 + i) * 8 + hk) * 64 + d4);
    }
    for (int x = t; x < 1024; x += 256) {
      const int i = x >> 4, cc = x & 15;
      S_pre[cb + i * 64 + cbase + cc] = S[i][cc];
    }
    __syncthreads();
    {
      float a0 = upre.x, a1 = upre.y, a2 = upre.z, a3 = upre.w;
      for (int e4 = 0; e4 < 64; e4 += 4) {
        const float4 wv4 = *(const float4*)&kw[row][e4];
#pragma unroll
        for (int ee = 0; ee < 4; ++ee) {
          const float wv = ((const float*)&wv4)[ee];
          const float4 sv = *(const float4*)&S[e4 + ee][c0];
          a0 -= wv * sv.x; a1 -= wv * sv.y; a2 -= wv * sv.z; a3 -= wv * sv.w;
        }
      }
      const float4 o = make_float4(a0, a1, a2, a3);
      *(float4*)&up[row][c0] = o;
      *(float4*)(u_p + cb + row * 64 + cbase + c0) = o;
    }
    __syncthreads();
    {
      const float4 sv = *(const float4*)&S[row][c0];
      float s0 = sv.x, s1 = sv.y, s2 = sv.z, s3 = sv.w;
      for (int i = 0; i < 64; ++i) {
        const float kv = kt[i][row];
        const float4 uv = *(const float4*)&up[i][c0];
        s0 += kv * uv.x; s1 += kv * uv.y; s2 += kv * uv.z; s3 += kv * uv.w;
      }
      *(float4*)&S[row][c0] = make_float4(s0, s1, s2, s3);
    }
    __syncthreads();
  }
}

// ---------------------------------------------------------------------------
// o_lin per (b,h,chunk).  1024 blocks.  Also emits q_bf = bf16(q_raw).
// ---------------------------------------------------------------------------
__global__ __launch_bounds__(256) void olin_k(
    const float* __restrict__ qraw, const float* __restrict__ kl,
    const float* __restrict__ upb, const float* __restrict__ S_pre,
    float* __restrict__ o_comb, bfu* __restrict__ q_bf)
{
  __shared__ float Q[64][65];
  __shared__ __align__(16) float Bb[64][68];
  __shared__ float At[64][65];
  const int blk = blockIdx.x;
  const int c = blk & 15, bh = blk >> 4;
  const int h = bh & 31, b = bh >> 5, hk = h >> 2;
  const int tid = threadIdx.x;
  const int i = tid >> 2, d0 = (tid & 3) * 16;
  for (int x = tid; x < 4096; x += 256) {
    const int r = x >> 6, d = x & 63;
    const size_t qidx = ((size_t)(b * Nc + c * 64 + r) * 32 + h) * 64 + d;
    const float qv = qraw[qidx];
    Q[r][d] = qv;
    q_bf[qidx] = f2bf(qv);
    Bb[d][r] = kl[((size_t)(b * Nc + c * 64 + r) * 8 + hk) * 64 + d];  // klT
  }
  __syncthreads();
  {
    float mx = -1e30f;
#pragma unroll
    for (int j = 0; j < 16; ++j) mx = fmaxf(mx, Q[i][d0 + j]);
#pragma unroll
    for (int o = 1; o < 4; o <<= 1) mx = fmaxf(mx, __shfl_xor(mx, o, 64));
    float ev[16];
    float sum = 0.f;
#pragma unroll
    for (int j = 0; j < 16; ++j) { ev[j] = __expf(Q[i][d0 + j] - mx); sum += ev[j]; }
#pragma unroll
    for (int o = 1; o < 4; o <<= 1) sum += __shfl_xor(sum, o, 64);
    const float inv = 1.f / sum;
#pragma unroll
    for (int j = 0; j < 16; ++j) Q[i][d0 + j] = ev[j] * inv;
  }
  __syncthreads();
  {
    float a[16];
#pragma unroll
    for (int j = 0; j < 16; ++j) a[j] = 0.f;
    for (int d = 0; d < 64; ++d) {
      const float qv = Q[i][d];
      const float4 b0 = *(const float4*)&Bb[d][d0];
      const float4 b1 = *(const float4*)&Bb[d][d0 + 4];
      const float4 b2 = *(const float4*)&Bb[d][d0 + 8];
      const float4 b3 = *(const float4*)&Bb[d][d0 + 12];
      a[0] += qv * b0.x;  a[1] += qv * b0.y;  a[2] += qv * b0.z;  a[3] += qv * b0.w;
      a[4] += qv * b1.x;  a[5] += qv * b1.y;  a[6] += qv * b1.z;  a[7] += qv * b1.w;
      a[8] += qv * b2.x;  a[9] += qv * b2.y;  a[10] += qv * b2.z; a[11] += qv * b2.w;
      a[12] += qv * b3.x; a[13] += qv * b3.y; a[14] += qv * b3.z; a[15] += qv * b3.w;
    }
#pragma unroll
    for (int j = 0; j < 16; ++j) At[i][d0 + j] = (d0 + j <= i) ? a[j] : 0.f;
  }
  __syncthreads();
  const size_t cb = ((size_t)(b * 8 + hk) * 16 + c) * 4096;
  for (int x = tid; x < 4096; x += 256) Bb[x >> 6][x & 63] = S_pre[cb + x];
  __syncthreads();
  float o[16];
#pragma unroll
  for (int j = 0; j < 16; ++j) o[j] = 0.f;
  for (int e = 0; e < 64; ++e) {
    const float qv = Q[i][e];
    const float4 b0 = *(const float4*)&Bb[e][d0];
    const float4 b1 = *(const float4*)&Bb[e][d0 + 4];
    const float4 b2 = *(const float4*)&Bb[e][d0 + 8];
    const float4 b3 = *(const float4*)&Bb[e][d0 + 12];
    o[0] += qv * b0.x;  o[1] += qv * b0.y;  o[2] += qv * b0.z;  o[3] += qv * b0.w;
    o[4] += qv * b1.x;  o[5] += qv * b1.y;  o[6] += qv * b1.z;  o[7] += qv * b1.w;
    o[8] += qv * b2.x;  o[9] += qv * b2.y;  o[10] += qv * b2.z; o[11] += qv * b2.w;
    o[12] += qv * b3.x; o[13] += qv * b3.y; o[14] += qv * b3.z; o[15] += qv * b3.w;
  }
  __syncthreads();
  for (int x = tid; x < 4096; x += 256) Bb[x >> 6][x & 63] = upb[cb + x];
  __syncthreads();
  for (int j2 = 0; j2 < 64; ++j2) {
    const float av = At[i][j2];
    const float4 b0 = *(const float4*)&Bb[j2][d0];
    const float4 b1 = *(const float4*)&Bb[j2][d0 + 4];
    const float4 b2 = *(const float4*)&Bb[j2][d0 + 8];
    const float4 b3 = *(const float4*)&Bb[j2][d0 + 12];
    o[0] += av * b0.x;  o[1] += av * b0.y;  o[2] += av * b0.z;  o[3] += av * b0.w;
    o[4] += av * b1.x;  o[5] += av * b1.y;  o[6] += av * b1.z;  o[7] += av * b1.w;
    o[8] += av * b2.x;  o[9] += av * b2.y;  o[10] += av * b2.z; o[11] += av * b2.w;
    o[12] += av * b3.x; o[13] += av * b3.y; o[14] += av * b3.z; o[15] += av * b3.w;
  }
  float* oc = o_comb + ((size_t)(b * Nc + c * 64 + i) * 32 + h) * 64 + d0;
#pragma unroll
  for (int j = 0; j < 16; ++j) oc[j] = 0.5f * o[j];
}

// ---------------------------------------------------------------------------
// Tile-copy helper: 64x64 bf16 tile global -> LDS [row][LDK], 2 uint4/thread.
// ---------------------------------------------------------------------------
template <int LDK>
__device__ __forceinline__ void stage_tile(
    const bfu* __restrict__ g, size_t row_stride, bfu* dst, int tid)
{
  const int xr = tid >> 3;         // 0..31
  const int xc = (tid & 7) * 8;    // 0,8,..,56
#pragma unroll
  for (int hh = 0; hh < 2; ++hh) {
    const int row = xr + hh * 32;
    *(uint4*)&dst[(size_t)row * LDK + xc] =
        *(const uint4*)(g + (size_t)row * row_stride + xc);
  }
}

// ---------------------------------------------------------------------------
// FUSED base attention (MFMA), coalesced p-write version:
// pass 1 online m,l; in-LDS reduce; pass 2 recompute scores -> p staged in
// fp32 LDS tile Pf (lanes write where values live), then COALESCED row-major
// copy Pf -> attn (16 consecutive threads = 256B contiguous) alongside PV.
// Q fragments loaded directly from global (Qt LDS dropped to fund Pf).
// oc_bf = bf16(o_comb + 0.5*o_base).  1024 blocks x 256 threads.
// ---------------------------------------------------------------------------
__global__ __launch_bounds__(256) void attn_mfma_k(
    const bfu* __restrict__ qbf, const bfu* __restrict__ kbf,
    const bfu* __restrict__ vtbf, float* __restrict__ attn,
    const float* __restrict__ o_comb, bfu* __restrict__ oc_bf)
{
  constexpr int LDK = 72;
  __shared__ __align__(16) bfu Kt[64 * LDK];    // [j][d]
  __shared__ __align__(16) bfu Vt[64 * LDK];    // [dv][j]
  __shared__ __align__(16) bfu Pmat[64 * LDK];  // [i][j] bf16 (PV A-operand)
  __shared__ __align__(16) float Pf[64][68];    // [i][j] fp32 (attn staging)
  __shared__ float mred[4][64];
  __shared__ float lred[4][64];
  __shared__ float mfin[64];
  __shared__ float lfin[64];
  const int blk = blockIdx.x;
  const int ib = blk & 15, bh = blk >> 4;
  const int h = bh & 31, b = bh >> 5, hk = h >> 2;
  const int tid = threadIdx.x;
  const int wave = tid >> 6, lane = tid & 63;
  const int fm = lane & 15, quad = lane >> 4;
  const int wj = wave * 16;   // score phase: wave's j slice
  const int im0 = wave * 16;  // PV phase: wave's i slice

  // Q fragments directly from global (one-time 16B loads per frag)
  frag_ab qb[4][2];
#pragma unroll
  for (int in = 0; in < 4; ++in)
#pragma unroll
    for (int kk = 0; kk < 2; ++kk)
      qb[in][kk] = *(const frag_ab*)(qbf +
          ((size_t)(b * Nc + ib * 64 + in * 16 + fm) * 32 + h) * 64 + kk * 32 + quad * 8);

  // ---- pass 1: online m,l ----
  float m[4], l[4];
#pragma unroll
  for (int in = 0; in < 4; ++in) { m[in] = -1e30f; l[in] = 0.f; }

  for (int jt = 0; jt <= ib; ++jt) {
    __syncthreads();
    stage_tile<LDK>(kbf + ((size_t)(b * Nc + jt * 64) * 8 + hk) * 64,
                    (size_t)8 * 64, Kt, tid);
    __syncthreads();
    frag_ab ka[2];
    ka[0] = *(const frag_ab*)&Kt[(size_t)(wj + fm) * LDK + quad * 8];
    ka[1] = *(const frag_ab*)&Kt[(size_t)(wj + fm) * LDK + 32 + quad * 8];
    const bool diag = (jt == ib);
#pragma unroll
    for (int in = 0; in < 4; ++in) {
      frag_cd acc = (frag_cd){0.f, 0.f, 0.f, 0.f};
      acc = __builtin_amdgcn_mfma_f32_16x16x32_bf16(ka[0], qb[in][0], acc, 0, 0, 0);
      acc = __builtin_amdgcn_mfma_f32_16x16x32_bf16(ka[1], qb[in][1], acc, 0, 0, 0);
      const int iloc = in * 16 + fm;
      float sv[4];
      bool vd[4];
      float tm = -1e30f;
#pragma unroll
      for (int r = 0; r < 4; ++r) {
        const int jloc = wj + quad * 4 + r;
        vd[r] = !diag || (jloc <= iloc);
        sv[r] = acc[r] * 0.125f;
        if (vd[r]) tm = fmaxf(tm, sv[r]);
      }
      const float mn = fmaxf(m[in], tm);
      float lsum = 0.f;
#pragma unroll
      for (int r = 0; r < 4; ++r)
        if (vd[r]) lsum += __expf(sv[r] - mn);
      l[in] = l[in] * __expf(m[in] - mn) + lsum;  // l==0 when m==-1e30, safe
      m[in] = mn;
    }
  }
  // reduce across quads then waves (same order as before)
#pragma unroll
  for (int in = 0; in < 4; ++in) {
    float mm = m[in], ll = l[in];
#pragma unroll
    for (int off = 16; off < 64; off <<= 1) {
      const float mo = __shfl_xor(mm, off, 64);
      const float lo = __shfl_xor(ll, off, 64);
      const float mn = fmaxf(mm, mo);
      ll = ll * __expf(mm - mn) + lo * __expf(mo - mn);
      mm = mn;
    }
    if (quad == 0) { mred[wave][in * 16 + fm] = mm; lred[wave][in * 16 + fm] = ll; }
  }
  __syncthreads();
  if (tid < 64) {
    float M = -1e30f;
#pragma unroll
    for (int w = 0; w < 4; ++w) M = fmaxf(M, mred[w][tid]);
    float L = 0.f;
#pragma unroll
    for (int w = 0; w < 4; ++w) L += lred[w][tid] * __expf(mred[w][tid] - M);
    mfin[tid] = M;
    lfin[tid] = L;
  }
  __syncthreads();
  float mi[4], il[4];
#pragma unroll
  for (int in = 0; in < 4; ++in) {
    mi[in] = mfin[in * 16 + fm];
    il[in] = 1.f / lfin[in * 16 + fm];
  }

  // ---- pass 2: p -> Pf/Pmat, then coalesced attn write + PV ----
  float* arow0 = attn + ((size_t)(b * 32 + h) * 1024 + ib * 64) * 1024;
  frag_cd o[4];
#pragma unroll
  for (int in = 0; in < 4; ++in) o[in] = (frag_cd){0.f, 0.f, 0.f, 0.f};

  for (int jt = 0; jt <= ib; ++jt) {
    __syncthreads();  // protect prev iter's Vt/Pmat/Pf reads
    stage_tile<LDK>(kbf + ((size_t)(b * Nc + jt * 64) * 8 + hk) * 64,
                    (size_t)8 * 64, Kt, tid);
    stage_tile<LDK>(vtbf + (size_t)(b * 8 + hk) * 64 * 1024 + jt * 64,
                    (size_t)1024, Vt, tid);
    __syncthreads();
    frag_ab ka[2];
    ka[0] = *(const frag_ab*)&Kt[(size_t)(wj + fm) * LDK + quad * 8];
    ka[1] = *(const frag_ab*)&Kt[(size_t)(wj + fm) * LDK + 32 + quad * 8];
    const bool diag = (jt == ib);
#pragma unroll
    for (int in = 0; in < 4; ++in) {
      frag_cd acc = (frag_cd){0.f, 0.f, 0.f, 0.f};
      acc = __builtin_amdgcn_mfma_f32_16x16x32_bf16(ka[0], qb[in][0], acc, 0, 0, 0);
      acc = __builtin_amdgcn_mfma_f32_16x16x32_bf16(ka[1], qb[in][1], acc, 0, 0, 0);
      const int iloc = in * 16 + fm;
      float p[4];
#pragma unroll
      for (int r = 0; r < 4; ++r) {
        const int jloc = wj + quad * 4 + r;
        const bool vdr = !diag || (jloc <= iloc);
        p[r] = vdr ? __expf(acc[r] * 0.125f - mi[in]) * il[in] : 0.f;
      }
      // stage fp32 p into Pf (attn staging) and bf16 into Pmat (PV operand)
      *(float4*)&Pf[iloc][wj + quad * 4] = make_float4(p[0], p[1], p[2], p[3]);
      ushort4 w;
      w.x = f2bf(p[0]); w.y = f2bf(p[1]); w.z = f2bf(p[2]); w.w = f2bf(p[3]);
      *(ushort4*)&Pmat[(size_t)iloc * LDK + wj + quad * 4] = w;
    }
    __syncthreads();
    // coalesced attn write: 16 consecutive threads cover one row's 64 cols
    for (int x = tid; x < 1024; x += 256) {
      const int row = x >> 4, c4 = (x & 15) * 4;
      *(float4*)(arow0 + (size_t)row * 1024 + jt * 64 + c4) =
          *(const float4*)&Pf[row][c4];
    }
    // PV: A = Pmat rows (wave's i slice), B = Vt rows (dv), k = j
    frag_ab pa[2];
    pa[0] = *(const frag_ab*)&Pmat[(size_t)(im0 + fm) * LDK + quad * 8];
    pa[1] = *(const frag_ab*)&Pmat[(size_t)(im0 + fm) * LDK + 32 + quad * 8];
#pragma unroll
    for (int in = 0; in < 4; ++in) {
      frag_ab vb0 = *(const frag_ab*)&Vt[(size_t)(in * 16 + fm) * LDK + quad * 8];
      frag_ab vb1 = *(const frag_ab*)&Vt[(size_t)(in * 16 + fm) * LDK + 32 + quad * 8];
      o[in] = __builtin_amdgcn_mfma_f32_16x16x32_bf16(pa[0], vb0, o[in], 0, 0, 0);
      o[in] = __builtin_amdgcn_mfma_f32_16x16x32_bf16(pa[1], vb1, o[in], 0, 0, 0);
    }
  }
  // zero-fill non-causal tiles of attn
  for (int jt2 = ib + 1; jt2 < 16; ++jt2) {
    const float4 z = make_float4(0.f, 0.f, 0.f, 0.f);
    for (int x = tid; x < 1024; x += 256) {
      const int row = x >> 4, c4 = (x & 15) * 4;
      *(float4*)(arow0 + (size_t)row * 1024 + jt2 * 64 + c4) = z;
    }
  }
  // oc_bf = bf16(o_comb + 0.5*o)
#pragma unroll
  for (int in = 0; in < 4; ++in)
#pragma unroll
    for (int r = 0; r < 4; ++r) {
      const int i = im0 + quad * 4 + r;
      const size_t idx = ((size_t)(b * Nc + ib * 64 + i) * 32 + h) * 64 + in * 16 + fm;
      oc_bf[idx] = f2bf(o_comb[idx] + 0.5f * o[in][r]);
    }
}

// ---------------------------------------------------------------------------
extern "C" void kernel_launch(void* const* d_in, const int* in_sizes, int n_in,
                              void* d_out, int out_size, void* d_ws, size_t ws_size,
                              hipStream_t stream) {
  const float* hs = (const float*)d_in[0];
  const float* Wq = (const float*)d_in[1];
  const float* Wk = (const float*)d_in[2];
  const float* Wv = (const float*)d_in[3];
  const float* Wo = (const float*)d_in[4];
  float* out = (float*)d_out;                      // [B,N,HID]
  float* attn = out + (size_t)Bc * Nc * HIDc;      // [B,H,N,N]

  float* ws = (float*)d_ws;
  float* q_raw  = ws;                     // 4,194,304 f32
  float* k_raw  = q_raw + 4194304;        // 1,048,576
  float* v_raw  = k_raw + 1048576;        // 1,048,576
  float* kl     = v_raw + 1048576;        // 1,048,576
  float* gl     = kl + 1048576;           // 1,048,576
  float* u_ps   = gl + 1048576;           // 2,097,152
  float* w_ps   = u_ps + 2097152;         // 2,097,152
  float* upb    = w_ps + 2097152;         // 2,097,152
  float* S_pre  = upb + 2097152;          // 2,097,152
  float* o_comb = S_pre + 2097152;        // 4,194,304
  float* mbuf   = o_comb + 4194304;       // 65,536 (unused, layout kept)
  float* lbuf   = mbuf + 65536;           // 65,536 (unused, layout kept)
  bfu* bstart = (bfu*)(lbuf + 65536);
  bfu* hs_bf  = bstart;                   // 4,194,304 bf16
  bfu* WqT    = hs_bf + 4194304;          // 4,194,304
  bfu* WkT    = WqT + 4194304;            // 1,048,576
  bfu* WvT    = WkT + 1048576;            // 1,048,576
  bfu* WoT    = WvT + 1048576;            // 4,194,304
  bfu* oc_bf  = WoT + 4194304;            // 4,194,304
  // Aliases of regions dead after gemm_qkv_k (stream-ordered, safe):
  bfu* q_bf   = hs_bf;                    // 4,194,304 bf16 (aliases hs_bf)
  bfu* k_bf   = WqT;                      // 1,048,576 bf16 (aliases WqT)
  bfu* vt_bf  = WqT + 1048576;            // 1,048,576 bf16 (aliases WqT+1M)

  // Fused prep: hs cast + 4 weight transposes in ONE dispatch
  prep_k<<<14336, 256, 0, stream>>>(hs, hs_bf, Wq, WqT, Wk, WkT,
                                    Wv, WvT, Wo, WoT);
  // Fused Q/K/V projection (bf16 MFMA, global_load_lds staging, 384 blocks)
  gemm_qkv_k<<<dim3(24, 16), 256, 0, stream>>>(hs_bf, WqT, WkT, WvT,
                                               q_raw, k_raw, v_raw);
  // Gates (also emits k_bf); V transpose (emits vt_bf)
  gates64_k<<<4096, 256, 0, stream>>>(k_raw, kl, gl, k_bf);
  transpose_v_k<<<256, 256, 0, stream>>>(v_raw, vt_bf);
  // Delta-rule
  chunk_prep_k<<<256, 256, 0, stream>>>(kl, v_raw, gl, u_ps, w_ps);
  scan_k<<<64, 256, 0, stream>>>(u_ps, w_ps, kl, upb, S_pre);
  // Linear-attention output (writes o_comb = 0.5*o_lin AND q_bf)
  olin_k<<<1024, 256, 0, stream>>>(q_raw, kl, upb, S_pre, o_comb, q_bf);
  // Fused base causal attention (coalesced p-writes via Pf staging)
  attn_mfma_k<<<1024, 256, 0, stream>>>(q_bf, k_bf, vt_bf, attn, o_comb, oc_bf);
  // Output projection (reads bf16 written by attn_mfma_k)
  gemm_wo_k<<<dim3(16, 16), 256, 0, stream>>>(oc_bf, WoT, out);
}